// Round 7
// baseline (506.698 us; speedup 1.0000x reference)
//
#include <hip/hip_runtime.h>

// ---------------------------------------------------------------------------
// MR_GNN: 2x (RGCN + GroupEnhance) + linear head.
// R8 -> R9: R8 post-mortem showed masked-FMA was free (VALU 42->13% but dur
// 49->55us): gather is latency/traffic-bound. FETCH=140MB for a 12.8MB X
// table = L2 thrash (4MB/XCD holds 1/3 of X). R9 feature-slices the gather:
// slice = blockIdx&1 (128B half-row); with round-robin block->XCD dispatch,
// even XCDs serve slice 0, odd slice 1 -> per-XCD X working set 6.4MB ~ L2.
// Wave = 8 edge-slots x 8 lanes, 2-deep unroll (16 edges in flight, same as
// R7), R7's proven masked 4-relation accumulators, 3-stage shfl reduce.
// MODE3 (group+head fusion) kept from R8. CSR build unchanged.
// ---------------------------------------------------------------------------

#define PART_EPB 2048  // edges per partition/hist block (256 thr x 8)

// ---- CSR build, pass A1: per-bucket edge counts (bucket = dst >> 8) ----
__global__ __launch_bounds__(256) void bucket_hist(const int* __restrict__ ei,
                                                   int* __restrict__ bcnt,
                                                   int E, int NB) {
    __shared__ int h[1024];
    for (int i = threadIdx.x; i < 1024; i += 256) h[i] = 0;
    __syncthreads();
    int base = blockIdx.x * PART_EPB;
#pragma unroll
    for (int k = 0; k < PART_EPB / 256; ++k) {
        int e = base + k * 256 + threadIdx.x;
        if (e < E) atomicAdd(&h[ei[E + e] >> 8], 1);
    }
    __syncthreads();
    for (int i = threadIdx.x; i < NB; i += 256)
        if (h[i]) atomicAdd(&bcnt[i], h[i]);
}

// ---- pass A-scan: exclusive scan of NB (<=1024) bucket counts ----
__global__ __launch_bounds__(1024) void bucket_scan(const int* __restrict__ bcnt,
                                                    int* __restrict__ bofs,
                                                    int* __restrict__ bcur,
                                                    int NB, int E) {
    __shared__ int lds[1024];
    int tid = threadIdx.x;
    int v = (tid < NB) ? bcnt[tid] : 0;
    lds[tid] = v;
    __syncthreads();
    int acc = v;
    for (int off = 1; off < 1024; off <<= 1) {
        int t = (tid >= off) ? lds[tid - off] : 0;
        __syncthreads();
        acc += t;
        lds[tid] = acc;
        __syncthreads();
    }
    int excl = acc - v;
    if (tid < NB) { bofs[tid] = excl; bcur[tid] = excl; }
    if (tid == 0) bofs[NB] = E;
}

// ---- pass A2: block-aggregated partition into bucket streams ----
__global__ __launch_bounds__(256) void partition(const int* __restrict__ ei,
                                                 const int* __restrict__ et,
                                                 const float* __restrict__ ew,
                                                 int* __restrict__ gcur,
                                                 int2* __restrict__ recA,
                                                 int* __restrict__ recB,
                                                 int E, int NB) {
    __shared__ int hist[1024];
    __shared__ int base[1024];
    const int tid = threadIdx.x;
    const int blockBase = blockIdx.x * PART_EPB;
    for (int i = tid; i < 1024; i += 256) hist[i] = 0;
    __syncthreads();
#pragma unroll
    for (int k = 0; k < PART_EPB / 256; ++k) {
        int e = blockBase + k * 256 + tid;
        if (e < E) atomicAdd(&hist[ei[E + e] >> 8], 1);
    }
    __syncthreads();
    for (int i = tid; i < NB; i += 256) {
        int h = hist[i];
        base[i] = h ? atomicAdd(&gcur[i], h) : 0;
    }
    __syncthreads();
    for (int i = tid; i < 1024; i += 256) hist[i] = 0;  // reuse as run cursor
    __syncthreads();
#pragma unroll
    for (int k = 0; k < PART_EPB / 256; ++k) {
        int e = blockBase + k * 256 + tid;
        if (e >= E) continue;
        int dst = ei[E + e];
        int b = dst >> 8;
        int pos = base[b] + atomicAdd(&hist[b], 1);
        recA[pos] = make_int2(ei[e], __float_as_int(ew[e]));
        recB[pos] = dst * 4 + et[e];
    }
}

// ---- pass B: per-bucket (node,rel) hist + scan in LDS, write rp2 + pw ----
__global__ __launch_bounds__(256) void bucket_fill(
    const int2* __restrict__ recA, const int* __restrict__ recB,
    const int* __restrict__ bofs, int* __restrict__ rp2, int2* __restrict__ pw,
    int N) {
    __shared__ int cnt[1024];
    __shared__ int cur[1024];
    __shared__ int wsum[4];
    const int b = blockIdx.x;
    const int tid = threadIdx.x;
    const int beg = bofs[b], end = bofs[b + 1];
    const int rebase = b << 10;  // base index in (dst*4+rel) space
    for (int j = 0; j < 4; ++j) cnt[tid * 4 + j] = 0;
    __syncthreads();
    for (int i = beg + tid; i < end; i += 256)
        atomicAdd(&cnt[recB[i] - rebase], 1);
    __syncthreads();
    int v[4];
    int s = 0;
#pragma unroll
    for (int j = 0; j < 4; ++j) { v[j] = cnt[tid * 4 + j]; s += v[j]; }
    int lane = tid & 63, wid = tid >> 6;
    int ws = s;
#pragma unroll
    for (int off = 1; off < 64; off <<= 1) {
        int t = __shfl_up(ws, off);
        if (lane >= off) ws += t;
    }
    if (lane == 63) wsum[wid] = ws;
    __syncthreads();
    int wb = 0;
    for (int w = 0; w < wid; ++w) wb += wsum[w];
    int run = beg + wb + ws - s;
#pragma unroll
    for (int j = 0; j < 4; ++j) {
        int idx = rebase + tid * 4 + j;
        if (idx <= 4 * N) rp2[idx] = run;
        cur[tid * 4 + j] = run;
        run += v[j];
    }
    __syncthreads();
    for (int i = beg + tid; i < end; i += 256) {
        int l = recB[i] - rebase;
        int p = atomicAdd(&cur[l], 1);
        pw[p] = recA[i];
    }
}

__device__ __forceinline__ void fma4(float4& a, float w, const float4& x) {
    a.x += w * x.x; a.y += w * x.y; a.z += w * x.z; a.w += w * x.w;
}

__device__ __forceinline__ float4 oct_reduce(float4 a) {
    // reduce over lane bits 3..5 (the 8 edge-slot groups)
#pragma unroll
    for (int off = 8; off < 64; off <<= 1) {
        a.x += __shfl_xor(a.x, off);
        a.y += __shfl_xor(a.y, off);
        a.z += __shfl_xor(a.z, off);
        a.w += __shfl_xor(a.w, off);
    }
    return a;
}

// ---------------------------------------------------------------------------
// Feature-sliced gather. Block = 4 nodes (1 per wave) x 1 feature slice;
// slice = blockIdx & 1 covers features [slice*32, slice*32+32) = one 128B
// L2 line per X row -> with round-robin block->XCD dispatch, each XCD's X
// working set is 6.4MB (~L2 capacity). Wave lanes: e = lane>>3 (8 edge
// slots, stride 8 over the node's unified [s0,s4) range, 2-deep unroll =
// 16 edges in flight), mm = lane&7 -> feature slice*32 + mm*4.
// REL=1: masked per-relation accumulators (edge position vs segment
//        bounds); after oct_reduce, slot group e==r stores relation r's
//        128B half-row. out: N x 256.
// REL=0: 2 accumulator chains, oct_reduce, slot group 0 stores. out: N x 64.
// ---------------------------------------------------------------------------
template <int REL>
__global__ __launch_bounds__(256) void gather_k(
    const float* __restrict__ X, const int* __restrict__ rp2,
    const int2* __restrict__ pw, float* __restrict__ out, int N) {
    int node = (blockIdx.x >> 1) * 4 + (threadIdx.x >> 6);
    if (node >= N) return;
    const int sl = blockIdx.x & 1;          // feature slice (XCD-pinned)
    const int lane = threadIdx.x & 63;
    const int e = lane >> 3, mm = lane & 7;
    const int fb = sl * 32 + mm * 4;        // feature base for this lane

    const int4 sv = *reinterpret_cast<const int4*>(rp2 + node * 4);
    const int s0 = sv.x, s1 = sv.y, s2 = sv.z, s3 = sv.w;
    const int s4 = rp2[node * 4 + 4];

    if (REL) {
        float4 A0 = make_float4(0.f, 0.f, 0.f, 0.f);
        float4 A1 = make_float4(0.f, 0.f, 0.f, 0.f);
        float4 A2 = make_float4(0.f, 0.f, 0.f, 0.f);
        float4 A3 = make_float4(0.f, 0.f, 0.f, 0.f);
        int i = s0 + e;
        for (; i + 8 < s4; i += 16) {  // 2 edges per slot in flight
            int2 e0 = pw[i];
            int2 e1 = pw[i + 8];
            float4 x0 = *reinterpret_cast<const float4*>(X + (size_t)e0.x * 64 + fb);
            float4 x1 = *reinterpret_cast<const float4*>(X + (size_t)e1.x * 64 + fb);
            float w0 = __int_as_float(e0.y), w1 = __int_as_float(e1.y);
            int j = i + 8;
            fma4(A0, (i < s1) ? w0 : 0.f, x0);
            fma4(A1, (i >= s1 && i < s2) ? w0 : 0.f, x0);
            fma4(A2, (i >= s2 && i < s3) ? w0 : 0.f, x0);
            fma4(A3, (i >= s3) ? w0 : 0.f, x0);
            fma4(A0, (j < s1) ? w1 : 0.f, x1);
            fma4(A1, (j >= s1 && j < s2) ? w1 : 0.f, x1);
            fma4(A2, (j >= s2 && j < s3) ? w1 : 0.f, x1);
            fma4(A3, (j >= s3) ? w1 : 0.f, x1);
        }
        if (i < s4) {
            int2 e0 = pw[i];
            float4 x0 = *reinterpret_cast<const float4*>(X + (size_t)e0.x * 64 + fb);
            float w0 = __int_as_float(e0.y);
            fma4(A0, (i < s1) ? w0 : 0.f, x0);
            fma4(A1, (i >= s1 && i < s2) ? w0 : 0.f, x0);
            fma4(A2, (i >= s2 && i < s3) ? w0 : 0.f, x0);
            fma4(A3, (i >= s3) ? w0 : 0.f, x0);
        }
        A0 = oct_reduce(A0);
        A1 = oct_reduce(A1);
        A2 = oct_reduce(A2);
        A3 = oct_reduce(A3);
        if (e < 4) {
            float4 o = (e == 0) ? A0 : (e == 1) ? A1 : (e == 2) ? A2 : A3;
            *reinterpret_cast<float4*>(out + (size_t)node * 256 + e * 64 + fb) = o;
        }
    } else {
        float4 A = make_float4(0.f, 0.f, 0.f, 0.f);
        float4 B = make_float4(0.f, 0.f, 0.f, 0.f);
        int i = s0 + e;
        for (; i + 8 < s4; i += 16) {
            int2 e0 = pw[i];
            int2 e1 = pw[i + 8];
            float4 x0 = *reinterpret_cast<const float4*>(X + (size_t)e0.x * 64 + fb);
            float4 x1 = *reinterpret_cast<const float4*>(X + (size_t)e1.x * 64 + fb);
            fma4(A, __int_as_float(e0.y), x0);
            fma4(B, __int_as_float(e1.y), x1);
        }
        if (i < s4) {
            int2 e0 = pw[i];
            float4 x0 = *reinterpret_cast<const float4*>(X + (size_t)e0.x * 64 + fb);
            fma4(A, __int_as_float(e0.y), x0);
        }
        A.x += B.x; A.y += B.y; A.z += B.z; A.w += B.w;
        A = oct_reduce(A);
        if (e == 0)
            *reinterpret_cast<float4*>(out + (size_t)node * 64 + fb) = A;
    }
}

// ---------------------------------------------------------------------------
// Node-side tiled GEMM (deg from rp2 row bounds).
// MODE 0 (rgcn):  OUT = relu((X@B0 + AGG@B1) / deg)            OUT: N x 64
// MODE 1 (group): OUT = X + alpha*((AGG@B0)/deg + bias)        OUT: N x 64
// MODE 3 (group+head): g = X + alpha*((AGG@B0)/deg + bias);
//                      OUT = g@B1 + bias2                      OUT: N x 32
// ---------------------------------------------------------------------------
template <int MODE>
__global__ __launch_bounds__(256) void node_gemm(
    const float* __restrict__ X, const float* __restrict__ AGG,
    const float* __restrict__ B0, const float* __restrict__ B1,
    const float* __restrict__ bias, const float* __restrict__ bias2,
    const float* __restrict__ alphap, const int* __restrict__ rp2,
    float* __restrict__ OUT, int N) {
    __shared__ float As[64][68];
    __shared__ float Bs[64][64];
    const int tid = threadIdx.x;
    const int tx = tid & 15, ty = tid >> 4;
    const int row0 = blockIdx.x * 64;
    float acc[4][4] = {};

    const int nchunks = (MODE == 0) ? 5 : 1;
    for (int c = 0; c < nchunks; ++c) {
        const float* A;
        int lda;
        const float* B;
        int ldb, bcols;
        if (MODE == 0) {
            if (c == 0) { A = X; lda = 64; B = B0; }
            else        { A = AGG + (c - 1) * 64; lda = 256; B = B1 + (size_t)(c - 1) * 64 * 64; }
            ldb = 64; bcols = 64;
        } else {
            A = AGG; lda = 64; B = B0; ldb = 64; bcols = 64;
        }
        if (c) __syncthreads();
#pragma unroll
        for (int q = 0; q < 4; ++q) {
            int f = q * 256 + tid;
            int r = f >> 4;
            int c4 = (f & 15) << 2;
            float4 v = make_float4(0.f, 0.f, 0.f, 0.f);
            int vr = row0 + r;
            if (vr < N) v = *reinterpret_cast<const float4*>(A + (size_t)vr * lda + c4);
            *reinterpret_cast<float4*>(&As[r][c4]) = v;
            float4 bv = make_float4(0.f, 0.f, 0.f, 0.f);
            if (c4 < bcols) bv = *reinterpret_cast<const float4*>(B + (size_t)r * ldb + c4);
            *reinterpret_cast<float4*>(&Bs[r][c4]) = bv;
        }
        __syncthreads();
#pragma unroll 8
        for (int k = 0; k < 64; ++k) {
            float4 b = *reinterpret_cast<const float4*>(&Bs[k][tx * 4]);
            float a0 = As[ty * 4 + 0][k];
            float a1 = As[ty * 4 + 1][k];
            float a2 = As[ty * 4 + 2][k];
            float a3 = As[ty * 4 + 3][k];
            acc[0][0] += a0 * b.x; acc[0][1] += a0 * b.y; acc[0][2] += a0 * b.z; acc[0][3] += a0 * b.w;
            acc[1][0] += a1 * b.x; acc[1][1] += a1 * b.y; acc[1][2] += a1 * b.z; acc[1][3] += a1 * b.w;
            acc[2][0] += a2 * b.x; acc[2][1] += a2 * b.y; acc[2][2] += a2 * b.z; acc[2][3] += a2 * b.w;
            acc[3][0] += a3 * b.x; acc[3][1] += a3 * b.y; acc[3][2] += a3 * b.z; acc[3][3] += a3 * b.w;
        }
    }

    const float alpha = (MODE == 1 || MODE == 3) ? alphap[0] : 0.f;

    if (MODE == 3) {
        // g = X + alpha*(acc/deg + bias) -> As (LDS); outW -> Bs; then
        // OUT = g @ outW + bias2 (64 -> 32).
        __syncthreads();  // main k-loop done everywhere before As/Bs reuse
#pragma unroll
        for (int i = 0; i < 4; ++i) {
            int vr = row0 + ty * 4 + i;
            float dg = 1.f;
            if (vr < N) dg = fmaxf((float)(rp2[vr * 4 + 4] - rp2[vr * 4]), 1.f);
#pragma unroll
            for (int j = 0; j < 4; ++j) {
                int col = tx * 4 + j;
                float g = 0.f;
                if (vr < N)
                    g = X[(size_t)vr * 64 + col] + alpha * (acc[i][j] / dg + bias[col]);
                As[ty * 4 + i][col] = g;
            }
        }
        // stage outW (64 x 32) into Bs[:][0..31]
#pragma unroll
        for (int t = 0; t < 2; ++t) {
            int idx = tid * 2 + t;        // 512 float4s
            int r = idx >> 3;
            int c4 = (idx & 7) << 2;
            *reinterpret_cast<float4*>(&Bs[r][c4]) =
                *reinterpret_cast<const float4*>(B1 + (size_t)r * 32 + c4);
        }
        __syncthreads();
        float acc2[4][2] = {};
#pragma unroll 8
        for (int k = 0; k < 64; ++k) {
            float b0 = Bs[k][tx * 2];
            float b1 = Bs[k][tx * 2 + 1];
#pragma unroll
            for (int i = 0; i < 4; ++i) {
                float a = As[ty * 4 + i][k];
                acc2[i][0] += a * b0;
                acc2[i][1] += a * b1;
            }
        }
#pragma unroll
        for (int i = 0; i < 4; ++i) {
            int vr = row0 + ty * 4 + i;
            if (vr >= N) continue;
#pragma unroll
            for (int j = 0; j < 2; ++j) {
                int col = tx * 2 + j;
                OUT[(size_t)vr * 32 + col] = acc2[i][j] + bias2[col];
            }
        }
        return;
    }

#pragma unroll
    for (int i = 0; i < 4; ++i) {
        int vr = row0 + ty * 4 + i;
        if (vr >= N) continue;
        float dg = fmaxf((float)(rp2[vr * 4 + 4] - rp2[vr * 4]), 1.f);
#pragma unroll
        for (int j = 0; j < 4; ++j) {
            int col = tx * 4 + j;
            if (MODE == 0) {
                OUT[(size_t)vr * 64 + col] = fmaxf(acc[i][j] / dg, 0.f);
            } else {
                OUT[(size_t)vr * 64 + col] =
                    X[(size_t)vr * 64 + col] + alpha * (acc[i][j] / dg + bias[col]);
            }
        }
    }
}

extern "C" void kernel_launch(void* const* d_in, const int* in_sizes, int n_in,
                              void* d_out, int out_size, void* d_ws, size_t ws_size,
                              hipStream_t stream) {
    const float* x      = (const float*)d_in[0];
    const int*   ei     = (const int*)d_in[1];
    const int*   et     = (const int*)d_in[2];
    const float* ew     = (const float*)d_in[3];
    const float* W1     = (const float*)d_in[4];
    const float* W01    = (const float*)d_in[5];
    const float* alpha1 = (const float*)d_in[6];
    const float* projW1 = (const float*)d_in[7];
    const float* projb1 = (const float*)d_in[8];
    const float* W2     = (const float*)d_in[9];
    const float* W02    = (const float*)d_in[10];
    const float* alpha2 = (const float*)d_in[11];
    const float* projW2 = (const float*)d_in[12];
    const float* projb2 = (const float*)d_in[13];
    const float* outW   = (const float*)d_in[14];
    const float* outb   = (const float*)d_in[15];
    const int N = in_sizes[0] / 64;
    const int E = in_sizes[2];
    const int M = 4 * N;            // (dst, rel) segments
    const int NB = (N + 255) >> 8;  // 256-node dst buckets

    // workspace (4-byte units):
    // bcnt[1024] | bofs[1032] | bcur[1024] | rp2[M+1 (+pad to even)] |
    // pw int2[E] | aggR[N*256] (recA int2[E] + recB int[E] aliased inside,
    // CSR-build only) | h[N*64] | g[N*64]
    int*   bcnt = (int*)d_ws;
    int*   bofs = bcnt + 1024;
    int*   bcur = bofs + 1032;
    int*   rp2  = bcur + 1024;
    int2*  pw   = (int2*)(rp2 + ((M + 2) & ~1));
    float* aggR = (float*)(pw + E);
    int2*  recA = (int2*)aggR;            // alias: dead once gather runs
    int*   recB = (int*)(recA + E);
    float* hbuf = aggR + (size_t)N * 256;
    float* gbuf = hbuf + (size_t)N * 64;
    (void)gbuf;

    const int gatherBlocks = ((N + 3) / 4) * 2;  // x2 feature slices
    const int gemmBlocks = (N + 63) / 64;
    const int pBlocks = (E + PART_EPB - 1) / PART_EPB;

    // ---- CSR build (block-aggregated radix partition, once per call) ----
    hipMemsetAsync(bcnt, 0, 1024 * sizeof(int), stream);
    bucket_hist<<<pBlocks, 256, 0, stream>>>(ei, bcnt, E, NB);
    bucket_scan<<<1, 1024, 0, stream>>>(bcnt, bofs, bcur, NB, E);
    partition<<<pBlocks, 256, 0, stream>>>(ei, et, ew, bcur, recA, recB, E, NB);
    bucket_fill<<<NB, 256, 0, stream>>>(recA, recB, bofs, rp2, pw, N);

    // ---- layer 1 ----
    gather_k<1><<<gatherBlocks, 256, 0, stream>>>(x, rp2, pw, aggR, N);
    node_gemm<0><<<gemmBlocks, 256, 0, stream>>>(x, aggR, W01, W1, nullptr, nullptr, nullptr, rp2, hbuf, N);
    gather_k<0><<<gatherBlocks, 256, 0, stream>>>(hbuf, rp2, pw, aggR, N);
    node_gemm<1><<<gemmBlocks, 256, 0, stream>>>(hbuf, aggR, projW1, nullptr, projb1, nullptr, alpha1, rp2, hbuf, N);

    // ---- layer 2 ----
    gather_k<1><<<gatherBlocks, 256, 0, stream>>>(hbuf, rp2, pw, aggR, N);
    node_gemm<0><<<gemmBlocks, 256, 0, stream>>>(hbuf, aggR, W02, W2, nullptr, nullptr, nullptr, rp2, hbuf, N);
    gather_k<0><<<gatherBlocks, 256, 0, stream>>>(hbuf, rp2, pw, aggR, N);
    // group + head fused: writes N x 32 output directly
    node_gemm<3><<<gemmBlocks, 256, 0, stream>>>(hbuf, aggR, projW2, outW, projb2, outb, alpha2, rp2, (float*)d_out, N);
}

// Round 8
// 442.075 us; speedup vs baseline: 1.1462x; 1.1462x over previous
//
#include <hip/hip_runtime.h>

// ---------------------------------------------------------------------------
// MR_GNN: 2x (RGCN + GroupEnhance) + linear head.
// R9 -> R10: R9's feature-slice regressed (FETCH 140->200MB: pw/rp2 read
// twice, 128B requests, 6.4MB/XCD still > 4MB L2). Restore R7's proven
// masked unified-range gather (49us, ~4TB/s = random-gather ceiling).
// New lever: fuse the ENTIRE group layer into the plain gather. After
// quad_reduce every lane holds agg[4m..4m+4); stage the row to a per-wave
// 256B LDS slice (in-wave DS ordering, no barrier), matvec y=agg/deg @ P
// via LDS-broadcast + L1-hot P column reads, write g = H + alpha*(y+pb)
// directly. Layer 2 adds the 64->32 head matvec in-kernel (writes Nx32).
// Deletes node_gemm<1>/<3> and two aggR round-trips (~38MB/layer).
// CSR build and rgcn node_gemm (MODE0) unchanged.
// ---------------------------------------------------------------------------

#define PART_EPB 2048  // edges per partition/hist block (256 thr x 8)

// ---- CSR build, pass A1: per-bucket edge counts (bucket = dst >> 8) ----
__global__ __launch_bounds__(256) void bucket_hist(const int* __restrict__ ei,
                                                   int* __restrict__ bcnt,
                                                   int E, int NB) {
    __shared__ int h[1024];
    for (int i = threadIdx.x; i < 1024; i += 256) h[i] = 0;
    __syncthreads();
    int base = blockIdx.x * PART_EPB;
#pragma unroll
    for (int k = 0; k < PART_EPB / 256; ++k) {
        int e = base + k * 256 + threadIdx.x;
        if (e < E) atomicAdd(&h[ei[E + e] >> 8], 1);
    }
    __syncthreads();
    for (int i = threadIdx.x; i < NB; i += 256)
        if (h[i]) atomicAdd(&bcnt[i], h[i]);
}

// ---- pass A-scan: exclusive scan of NB (<=1024) bucket counts ----
__global__ __launch_bounds__(1024) void bucket_scan(const int* __restrict__ bcnt,
                                                    int* __restrict__ bofs,
                                                    int* __restrict__ bcur,
                                                    int NB, int E) {
    __shared__ int lds[1024];
    int tid = threadIdx.x;
    int v = (tid < NB) ? bcnt[tid] : 0;
    lds[tid] = v;
    __syncthreads();
    int acc = v;
    for (int off = 1; off < 1024; off <<= 1) {
        int t = (tid >= off) ? lds[tid - off] : 0;
        __syncthreads();
        acc += t;
        lds[tid] = acc;
        __syncthreads();
    }
    int excl = acc - v;
    if (tid < NB) { bofs[tid] = excl; bcur[tid] = excl; }
    if (tid == 0) bofs[NB] = E;
}

// ---- pass A2: block-aggregated partition into bucket streams ----
__global__ __launch_bounds__(256) void partition(const int* __restrict__ ei,
                                                 const int* __restrict__ et,
                                                 const float* __restrict__ ew,
                                                 int* __restrict__ gcur,
                                                 int2* __restrict__ recA,
                                                 int* __restrict__ recB,
                                                 int E, int NB) {
    __shared__ int hist[1024];
    __shared__ int base[1024];
    const int tid = threadIdx.x;
    const int blockBase = blockIdx.x * PART_EPB;
    for (int i = tid; i < 1024; i += 256) hist[i] = 0;
    __syncthreads();
#pragma unroll
    for (int k = 0; k < PART_EPB / 256; ++k) {
        int e = blockBase + k * 256 + tid;
        if (e < E) atomicAdd(&hist[ei[E + e] >> 8], 1);
    }
    __syncthreads();
    for (int i = tid; i < NB; i += 256) {
        int h = hist[i];
        base[i] = h ? atomicAdd(&gcur[i], h) : 0;
    }
    __syncthreads();
    for (int i = tid; i < 1024; i += 256) hist[i] = 0;  // reuse as run cursor
    __syncthreads();
#pragma unroll
    for (int k = 0; k < PART_EPB / 256; ++k) {
        int e = blockBase + k * 256 + tid;
        if (e >= E) continue;
        int dst = ei[E + e];
        int b = dst >> 8;
        int pos = base[b] + atomicAdd(&hist[b], 1);
        recA[pos] = make_int2(ei[e], __float_as_int(ew[e]));
        recB[pos] = dst * 4 + et[e];
    }
}

// ---- pass B: per-bucket (node,rel) hist + scan in LDS, write rp2 + pw ----
__global__ __launch_bounds__(256) void bucket_fill(
    const int2* __restrict__ recA, const int* __restrict__ recB,
    const int* __restrict__ bofs, int* __restrict__ rp2, int2* __restrict__ pw,
    int N) {
    __shared__ int cnt[1024];
    __shared__ int cur[1024];
    __shared__ int wsum[4];
    const int b = blockIdx.x;
    const int tid = threadIdx.x;
    const int beg = bofs[b], end = bofs[b + 1];
    const int rebase = b << 10;  // base index in (dst*4+rel) space
    for (int j = 0; j < 4; ++j) cnt[tid * 4 + j] = 0;
    __syncthreads();
    for (int i = beg + tid; i < end; i += 256)
        atomicAdd(&cnt[recB[i] - rebase], 1);
    __syncthreads();
    int v[4];
    int s = 0;
#pragma unroll
    for (int j = 0; j < 4; ++j) { v[j] = cnt[tid * 4 + j]; s += v[j]; }
    int lane = tid & 63, wid = tid >> 6;
    int ws = s;
#pragma unroll
    for (int off = 1; off < 64; off <<= 1) {
        int t = __shfl_up(ws, off);
        if (lane >= off) ws += t;
    }
    if (lane == 63) wsum[wid] = ws;
    __syncthreads();
    int wb = 0;
    for (int w = 0; w < wid; ++w) wb += wsum[w];
    int run = beg + wb + ws - s;
#pragma unroll
    for (int j = 0; j < 4; ++j) {
        int idx = rebase + tid * 4 + j;
        if (idx <= 4 * N) rp2[idx] = run;
        cur[tid * 4 + j] = run;
        run += v[j];
    }
    __syncthreads();
    for (int i = beg + tid; i < end; i += 256) {
        int l = recB[i] - rebase;
        int p = atomicAdd(&cur[l], 1);
        pw[p] = recA[i];
    }
}

__device__ __forceinline__ float4 quad_reduce(float4 a) {
#pragma unroll
    for (int off = 16; off < 64; off <<= 1) {
        a.x += __shfl_xor(a.x, off);
        a.y += __shfl_xor(a.y, off);
        a.z += __shfl_xor(a.z, off);
        a.w += __shfl_xor(a.w, off);
    }
    return a;
}

__device__ __forceinline__ void fma4(float4& a, float w, const float4& x) {
    a.x += w * x.x; a.y += w * x.y; a.z += w * x.z; a.w += w * x.w;
}

// ---------------------------------------------------------------------------
// Relation gather (R7 form, proven 49us). One wave per node; lane = 16*q+m:
// quarter q handles edges s0+q+4k of the unified [s0,s4) range; masked
// per-relation accumulators; epilogue: quad_reduce x4, quarter q stores
// relation-q's row. out: N x 256.
// ---------------------------------------------------------------------------
__global__ __launch_bounds__(256) void gather_rel(
    const float* __restrict__ X, const int* __restrict__ rp2,
    const int2* __restrict__ pw, float* __restrict__ out, int N) {
    int node = blockIdx.x * 4 + (threadIdx.x >> 6);
    if (node >= N) return;
    int lane = threadIdx.x & 63;
    int q = lane >> 4, m = lane & 15;
    const int4 sv = *reinterpret_cast<const int4*>(rp2 + node * 4);
    const int s0 = sv.x, s1 = sv.y, s2 = sv.z, s3 = sv.w;
    const int s4 = rp2[node * 4 + 4];
    float4 A0 = make_float4(0.f, 0.f, 0.f, 0.f);
    float4 A1 = make_float4(0.f, 0.f, 0.f, 0.f);
    float4 A2 = make_float4(0.f, 0.f, 0.f, 0.f);
    float4 A3 = make_float4(0.f, 0.f, 0.f, 0.f);

    auto accum = [&](int idx, int2 e, const float4& xv) {
        float w = __int_as_float(e.y);
        fma4(A0, (idx < s1) ? w : 0.f, xv);
        fma4(A1, (idx >= s1 && idx < s2) ? w : 0.f, xv);
        fma4(A2, (idx >= s2 && idx < s3) ? w : 0.f, xv);
        fma4(A3, (idx >= s3) ? w : 0.f, xv);
    };

    int i = s0 + q;
    for (; i + 12 < s4; i += 16) {  // 4 gathers in flight
        int2 e0 = pw[i];
        int2 e1 = pw[i + 4];
        int2 e2 = pw[i + 8];
        int2 e3 = pw[i + 12];
        float4 x0 = *reinterpret_cast<const float4*>(X + (size_t)e0.x * 64 + m * 4);
        float4 x1 = *reinterpret_cast<const float4*>(X + (size_t)e1.x * 64 + m * 4);
        float4 x2 = *reinterpret_cast<const float4*>(X + (size_t)e2.x * 64 + m * 4);
        float4 x3 = *reinterpret_cast<const float4*>(X + (size_t)e3.x * 64 + m * 4);
        accum(i, e0, x0);
        accum(i + 4, e1, x1);
        accum(i + 8, e2, x2);
        accum(i + 12, e3, x3);
    }
    for (; i + 4 < s4; i += 8) {  // 2 in flight
        int2 e0 = pw[i];
        int2 e1 = pw[i + 4];
        float4 x0 = *reinterpret_cast<const float4*>(X + (size_t)e0.x * 64 + m * 4);
        float4 x1 = *reinterpret_cast<const float4*>(X + (size_t)e1.x * 64 + m * 4);
        accum(i, e0, x0);
        accum(i + 4, e1, x1);
    }
    if (i < s4) {
        int2 e0 = pw[i];
        float4 x0 = *reinterpret_cast<const float4*>(X + (size_t)e0.x * 64 + m * 4);
        accum(i, e0, x0);
    }

    A0 = quad_reduce(A0);
    A1 = quad_reduce(A1);
    A2 = quad_reduce(A2);
    A3 = quad_reduce(A3);
    float4 o = (q == 0) ? A0 : (q == 1) ? A1 : (q == 2) ? A2 : A3;
    *reinterpret_cast<float4*>(out + (size_t)node * 256 + q * 64 + m * 4) = o;
}

// ---------------------------------------------------------------------------
// Fused GroupEnhance (+ optional head). Plain gather (R7 REL=0 body) then:
// every lane holds agg[4m..4m+4) after quad_reduce; q==0 lanes stage the
// deg-normalized row into this wave's private 256B LDS slice (in-wave DS
// ordering: no barrier needed), each lane computes y[lane] = agg/deg @ P
// (LDS-broadcast reads + coalesced L1-hot P column reads, 4 FMA chains),
// g = H + alpha*(y + pb).
// HEAD=0: writes g row (coalesced 64 floats/wave).      out: N x 64
// HEAD=1: stages g to LDS, second matvec g @ OW (64->32), lanes<32 store.
//                                                        out: N x 32
// ---------------------------------------------------------------------------
template <int HEAD>
__global__ __launch_bounds__(256) void group_fused(
    const float* __restrict__ H, const int* __restrict__ rp2,
    const int2* __restrict__ pw, const float* __restrict__ P,
    const float* __restrict__ pb, const float* __restrict__ alphap,
    const float* __restrict__ OW, const float* __restrict__ ob,
    float* __restrict__ out, int N) {
    __shared__ float ag_lds[4][64];
    __shared__ float g_lds[4][64];
    const int wv = threadIdx.x >> 6;
    const int node = blockIdx.x * 4 + wv;
    if (node >= N) return;
    const int lane = threadIdx.x & 63;
    const int q = lane >> 4, m = lane & 15;
    const int s0 = rp2[node * 4];
    const int s4 = rp2[node * 4 + 4];

    float4 A0 = make_float4(0.f, 0.f, 0.f, 0.f);
    float4 A1 = make_float4(0.f, 0.f, 0.f, 0.f);
    float4 A2 = make_float4(0.f, 0.f, 0.f, 0.f);
    float4 A3 = make_float4(0.f, 0.f, 0.f, 0.f);
    int i = s0 + q;
    for (; i + 12 < s4; i += 16) {  // 4 gathers in flight per quarter
        int2 e0 = pw[i];
        int2 e1 = pw[i + 4];
        int2 e2 = pw[i + 8];
        int2 e3 = pw[i + 12];
        float4 x0 = *reinterpret_cast<const float4*>(H + (size_t)e0.x * 64 + m * 4);
        float4 x1 = *reinterpret_cast<const float4*>(H + (size_t)e1.x * 64 + m * 4);
        float4 x2 = *reinterpret_cast<const float4*>(H + (size_t)e2.x * 64 + m * 4);
        float4 x3 = *reinterpret_cast<const float4*>(H + (size_t)e3.x * 64 + m * 4);
        fma4(A0, __int_as_float(e0.y), x0);
        fma4(A1, __int_as_float(e1.y), x1);
        fma4(A2, __int_as_float(e2.y), x2);
        fma4(A3, __int_as_float(e3.y), x3);
    }
    for (; i + 4 < s4; i += 8) {
        int2 e0 = pw[i];
        int2 e1 = pw[i + 4];
        float4 x0 = *reinterpret_cast<const float4*>(H + (size_t)e0.x * 64 + m * 4);
        float4 x1 = *reinterpret_cast<const float4*>(H + (size_t)e1.x * 64 + m * 4);
        fma4(A0, __int_as_float(e0.y), x0);
        fma4(A1, __int_as_float(e1.y), x1);
    }
    if (i < s4) {
        int2 e0 = pw[i];
        float4 x0 = *reinterpret_cast<const float4*>(H + (size_t)e0.x * 64 + m * 4);
        fma4(A0, __int_as_float(e0.y), x0);
    }
    A0.x += A1.x + A2.x + A3.x;
    A0.y += A1.y + A2.y + A3.y;
    A0.z += A1.z + A2.z + A3.z;
    A0.w += A1.w + A2.w + A3.w;
    A0 = quad_reduce(A0);  // all lanes now hold agg[4m..4m+4)

    const float dg = fmaxf((float)(s4 - s0), 1.f);
    if (q == 0) {
        float4 agd = make_float4(A0.x / dg, A0.y / dg, A0.z / dg, A0.w / dg);
        *reinterpret_cast<float4*>(&ag_lds[wv][m * 4]) = agd;
    }
    // In-wave DS ordering: the ds_reads below issue after the ds_write above
    // in program order for this wave; LDS ops of one wave complete in order.

    // y[lane] = (agg/deg) @ P, column `lane`; 4 independent FMA chains.
    float y0 = 0.f, y1 = 0.f, y2 = 0.f, y3 = 0.f;
#pragma unroll
    for (int kk = 0; kk < 16; ++kk) {
        float4 a = *reinterpret_cast<const float4*>(&ag_lds[wv][kk * 4]);
        y0 += a.x * P[(size_t)(kk * 4 + 0) * 64 + lane];
        y1 += a.y * P[(size_t)(kk * 4 + 1) * 64 + lane];
        y2 += a.z * P[(size_t)(kk * 4 + 2) * 64 + lane];
        y3 += a.w * P[(size_t)(kk * 4 + 3) * 64 + lane];
    }
    const float alpha = alphap[0];
    const float g = H[(size_t)node * 64 + lane] +
                    alpha * (((y0 + y1) + (y2 + y3)) + pb[lane]);

    if (!HEAD) {
        out[(size_t)node * 64 + lane] = g;  // 64 consecutive floats per wave
    } else {
        g_lds[wv][lane] = g;
        // same in-wave DS ordering argument as above
        const int c = lane & 31;
        float o0 = 0.f, o1 = 0.f, o2 = 0.f, o3 = 0.f;
#pragma unroll
        for (int kk = 0; kk < 16; ++kk) {
            float4 gv = *reinterpret_cast<const float4*>(&g_lds[wv][kk * 4]);
            o0 += gv.x * OW[(size_t)(kk * 4 + 0) * 32 + c];
            o1 += gv.y * OW[(size_t)(kk * 4 + 1) * 32 + c];
            o2 += gv.z * OW[(size_t)(kk * 4 + 2) * 32 + c];
            o3 += gv.w * OW[(size_t)(kk * 4 + 3) * 32 + c];
        }
        if (lane < 32)
            out[(size_t)node * 32 + c] = ((o0 + o1) + (o2 + o3)) + ob[c];
    }
}

// ---------------------------------------------------------------------------
// RGCN node GEMM: OUT = relu((X@B0 + sum_r AGG_r@B1_r) / deg)   OUT: N x 64
// ---------------------------------------------------------------------------
__global__ __launch_bounds__(256) void rgcn_gemm(
    const float* __restrict__ X, const float* __restrict__ AGG,
    const float* __restrict__ B0, const float* __restrict__ B1,
    const int* __restrict__ rp2, float* __restrict__ OUT, int N) {
    __shared__ float As[64][68];
    __shared__ float Bs[64][64];
    const int tid = threadIdx.x;
    const int tx = tid & 15, ty = tid >> 4;
    const int row0 = blockIdx.x * 64;
    float acc[4][4] = {};

    for (int c = 0; c < 5; ++c) {
        const float* A;
        int lda;
        const float* B;
        if (c == 0) { A = X; lda = 64; B = B0; }
        else        { A = AGG + (c - 1) * 64; lda = 256; B = B1 + (size_t)(c - 1) * 64 * 64; }
        if (c) __syncthreads();
#pragma unroll
        for (int q = 0; q < 4; ++q) {
            int f = q * 256 + tid;
            int r = f >> 4;
            int c4 = (f & 15) << 2;
            float4 v = make_float4(0.f, 0.f, 0.f, 0.f);
            int vr = row0 + r;
            if (vr < N) v = *reinterpret_cast<const float4*>(A + (size_t)vr * lda + c4);
            *reinterpret_cast<float4*>(&As[r][c4]) = v;
            *reinterpret_cast<float4*>(&Bs[r][c4]) =
                *reinterpret_cast<const float4*>(B + (size_t)r * 64 + c4);
        }
        __syncthreads();
#pragma unroll 8
        for (int k = 0; k < 64; ++k) {
            float4 b = *reinterpret_cast<const float4*>(&Bs[k][tx * 4]);
            float a0 = As[ty * 4 + 0][k];
            float a1 = As[ty * 4 + 1][k];
            float a2 = As[ty * 4 + 2][k];
            float a3 = As[ty * 4 + 3][k];
            acc[0][0] += a0 * b.x; acc[0][1] += a0 * b.y; acc[0][2] += a0 * b.z; acc[0][3] += a0 * b.w;
            acc[1][0] += a1 * b.x; acc[1][1] += a1 * b.y; acc[1][2] += a1 * b.z; acc[1][3] += a1 * b.w;
            acc[2][0] += a2 * b.x; acc[2][1] += a2 * b.y; acc[2][2] += a2 * b.z; acc[2][3] += a2 * b.w;
            acc[3][0] += a3 * b.x; acc[3][1] += a3 * b.y; acc[3][2] += a3 * b.z; acc[3][3] += a3 * b.w;
        }
    }

#pragma unroll
    for (int i = 0; i < 4; ++i) {
        int vr = row0 + ty * 4 + i;
        if (vr >= N) continue;
        float dg = fmaxf((float)(rp2[vr * 4 + 4] - rp2[vr * 4]), 1.f);
#pragma unroll
        for (int j = 0; j < 4; ++j) {
            int col = tx * 4 + j;
            OUT[(size_t)vr * 64 + col] = fmaxf(acc[i][j] / dg, 0.f);
        }
    }
}

extern "C" void kernel_launch(void* const* d_in, const int* in_sizes, int n_in,
                              void* d_out, int out_size, void* d_ws, size_t ws_size,
                              hipStream_t stream) {
    const float* x      = (const float*)d_in[0];
    const int*   ei     = (const int*)d_in[1];
    const int*   et     = (const int*)d_in[2];
    const float* ew     = (const float*)d_in[3];
    const float* W1     = (const float*)d_in[4];
    const float* W01    = (const float*)d_in[5];
    const float* alpha1 = (const float*)d_in[6];
    const float* projW1 = (const float*)d_in[7];
    const float* projb1 = (const float*)d_in[8];
    const float* W2     = (const float*)d_in[9];
    const float* W02    = (const float*)d_in[10];
    const float* alpha2 = (const float*)d_in[11];
    const float* projW2 = (const float*)d_in[12];
    const float* projb2 = (const float*)d_in[13];
    const float* outW   = (const float*)d_in[14];
    const float* outb   = (const float*)d_in[15];
    const int N = in_sizes[0] / 64;
    const int E = in_sizes[2];
    const int M = 4 * N;            // (dst, rel) segments
    const int NB = (N + 255) >> 8;  // 256-node dst buckets

    // workspace (4-byte units):
    // bcnt[1024] | bofs[1032] | bcur[1024] | rp2[M+1 (+pad to even)] |
    // pw int2[E] | aggR[N*256] (recA int2[E] + recB int[E] aliased inside,
    // CSR-build only) | h[N*64] | g[N*64]
    int*   bcnt = (int*)d_ws;
    int*   bofs = bcnt + 1024;
    int*   bcur = bofs + 1032;
    int*   rp2  = bcur + 1024;
    int2*  pw   = (int2*)(rp2 + ((M + 2) & ~1));
    float* aggR = (float*)(pw + E);
    int2*  recA = (int2*)aggR;            // alias: dead once gather runs
    int*   recB = (int*)(recA + E);
    float* hbuf = aggR + (size_t)N * 256;
    float* gbuf = hbuf + (size_t)N * 64;

    const int gatherBlocks = (N + 3) / 4;
    const int gemmBlocks = (N + 63) / 64;
    const int pBlocks = (E + PART_EPB - 1) / PART_EPB;

    // ---- CSR build (block-aggregated radix partition, once per call) ----
    hipMemsetAsync(bcnt, 0, 1024 * sizeof(int), stream);
    bucket_hist<<<pBlocks, 256, 0, stream>>>(ei, bcnt, E, NB);
    bucket_scan<<<1, 1024, 0, stream>>>(bcnt, bofs, bcur, NB, E);
    partition<<<pBlocks, 256, 0, stream>>>(ei, et, ew, bcur, recA, recB, E, NB);
    bucket_fill<<<NB, 256, 0, stream>>>(recA, recB, bofs, rp2, pw, N);

    // ---- layer 1 ----
    gather_rel<<<gatherBlocks, 256, 0, stream>>>(x, rp2, pw, aggR, N);
    rgcn_gemm<<<gemmBlocks, 256, 0, stream>>>(x, aggR, W01, W1, rp2, hbuf, N);
    group_fused<0><<<gatherBlocks, 256, 0, stream>>>(hbuf, rp2, pw, projW1, projb1,
                                                     alpha1, nullptr, nullptr, gbuf, N);

    // ---- layer 2 ----
    gather_rel<<<gatherBlocks, 256, 0, stream>>>(gbuf, rp2, pw, aggR, N);
    rgcn_gemm<<<gemmBlocks, 256, 0, stream>>>(gbuf, aggR, W02, W2, rp2, hbuf, N);
    // group + head fused: writes N x 32 output directly
    group_fused<1><<<gatherBlocks, 256, 0, stream>>>(hbuf, rp2, pw, projW2, projb2,
                                                     alpha2, outW, outb, (float*)d_out, N);
}

// Round 9
// 436.145 us; speedup vs baseline: 1.1618x; 1.0136x over previous
//
#include <hip/hip_runtime.h>

// ---------------------------------------------------------------------------
// MR_GNN: 2x (RGCN + GroupEnhance) + linear head.
// R10 -> R11 (consolidation): R10's gather+group fusion lost (77.8us vs ~54
// split; per-wave matvec tail throttles the memory pipeline: hbm 4.0->1.9
// TB/s). Best measured combo, never run together:
//   - R7 gathers verbatim (masked unified-range REL=1 @49us, 4-chain REL=0
//     @44us -- both at the ~4TB/s random-gather ceiling),
//   - R7 MODE0/MODE1 tiled GEMMs,
//   - R8's MODE3 head fusion (the part of R8 that worked).
// CSR build unchanged (block-aggregated radix partition).
// ---------------------------------------------------------------------------

#define PART_EPB 2048  // edges per partition/hist block (256 thr x 8)

// ---- CSR build, pass A1: per-bucket edge counts (bucket = dst >> 8) ----
__global__ __launch_bounds__(256) void bucket_hist(const int* __restrict__ ei,
                                                   int* __restrict__ bcnt,
                                                   int E, int NB) {
    __shared__ int h[1024];
    for (int i = threadIdx.x; i < 1024; i += 256) h[i] = 0;
    __syncthreads();
    int base = blockIdx.x * PART_EPB;
#pragma unroll
    for (int k = 0; k < PART_EPB / 256; ++k) {
        int e = base + k * 256 + threadIdx.x;
        if (e < E) atomicAdd(&h[ei[E + e] >> 8], 1);
    }
    __syncthreads();
    for (int i = threadIdx.x; i < NB; i += 256)
        if (h[i]) atomicAdd(&bcnt[i], h[i]);
}

// ---- pass A-scan: exclusive scan of NB (<=1024) bucket counts ----
__global__ __launch_bounds__(1024) void bucket_scan(const int* __restrict__ bcnt,
                                                    int* __restrict__ bofs,
                                                    int* __restrict__ bcur,
                                                    int NB, int E) {
    __shared__ int lds[1024];
    int tid = threadIdx.x;
    int v = (tid < NB) ? bcnt[tid] : 0;
    lds[tid] = v;
    __syncthreads();
    int acc = v;
    for (int off = 1; off < 1024; off <<= 1) {
        int t = (tid >= off) ? lds[tid - off] : 0;
        __syncthreads();
        acc += t;
        lds[tid] = acc;
        __syncthreads();
    }
    int excl = acc - v;
    if (tid < NB) { bofs[tid] = excl; bcur[tid] = excl; }
    if (tid == 0) bofs[NB] = E;
}

// ---- pass A2: block-aggregated partition into bucket streams ----
__global__ __launch_bounds__(256) void partition(const int* __restrict__ ei,
                                                 const int* __restrict__ et,
                                                 const float* __restrict__ ew,
                                                 int* __restrict__ gcur,
                                                 int2* __restrict__ recA,
                                                 int* __restrict__ recB,
                                                 int E, int NB) {
    __shared__ int hist[1024];
    __shared__ int base[1024];
    const int tid = threadIdx.x;
    const int blockBase = blockIdx.x * PART_EPB;
    for (int i = tid; i < 1024; i += 256) hist[i] = 0;
    __syncthreads();
#pragma unroll
    for (int k = 0; k < PART_EPB / 256; ++k) {
        int e = blockBase + k * 256 + tid;
        if (e < E) atomicAdd(&hist[ei[E + e] >> 8], 1);
    }
    __syncthreads();
    for (int i = tid; i < NB; i += 256) {
        int h = hist[i];
        base[i] = h ? atomicAdd(&gcur[i], h) : 0;
    }
    __syncthreads();
    for (int i = tid; i < 1024; i += 256) hist[i] = 0;  // reuse as run cursor
    __syncthreads();
#pragma unroll
    for (int k = 0; k < PART_EPB / 256; ++k) {
        int e = blockBase + k * 256 + tid;
        if (e >= E) continue;
        int dst = ei[E + e];
        int b = dst >> 8;
        int pos = base[b] + atomicAdd(&hist[b], 1);
        recA[pos] = make_int2(ei[e], __float_as_int(ew[e]));
        recB[pos] = dst * 4 + et[e];
    }
}

// ---- pass B: per-bucket (node,rel) hist + scan in LDS, write rp2 + pw ----
__global__ __launch_bounds__(256) void bucket_fill(
    const int2* __restrict__ recA, const int* __restrict__ recB,
    const int* __restrict__ bofs, int* __restrict__ rp2, int2* __restrict__ pw,
    int N) {
    __shared__ int cnt[1024];
    __shared__ int cur[1024];
    __shared__ int wsum[4];
    const int b = blockIdx.x;
    const int tid = threadIdx.x;
    const int beg = bofs[b], end = bofs[b + 1];
    const int rebase = b << 10;  // base index in (dst*4+rel) space
    for (int j = 0; j < 4; ++j) cnt[tid * 4 + j] = 0;
    __syncthreads();
    for (int i = beg + tid; i < end; i += 256)
        atomicAdd(&cnt[recB[i] - rebase], 1);
    __syncthreads();
    int v[4];
    int s = 0;
#pragma unroll
    for (int j = 0; j < 4; ++j) { v[j] = cnt[tid * 4 + j]; s += v[j]; }
    int lane = tid & 63, wid = tid >> 6;
    int ws = s;
#pragma unroll
    for (int off = 1; off < 64; off <<= 1) {
        int t = __shfl_up(ws, off);
        if (lane >= off) ws += t;
    }
    if (lane == 63) wsum[wid] = ws;
    __syncthreads();
    int wb = 0;
    for (int w = 0; w < wid; ++w) wb += wsum[w];
    int run = beg + wb + ws - s;
#pragma unroll
    for (int j = 0; j < 4; ++j) {
        int idx = rebase + tid * 4 + j;
        if (idx <= 4 * N) rp2[idx] = run;
        cur[tid * 4 + j] = run;
        run += v[j];
    }
    __syncthreads();
    for (int i = beg + tid; i < end; i += 256) {
        int l = recB[i] - rebase;
        int p = atomicAdd(&cur[l], 1);
        pw[p] = recA[i];
    }
}

__device__ __forceinline__ float4 quad_reduce(float4 a) {
#pragma unroll
    for (int off = 16; off < 64; off <<= 1) {
        a.x += __shfl_xor(a.x, off);
        a.y += __shfl_xor(a.y, off);
        a.z += __shfl_xor(a.z, off);
        a.w += __shfl_xor(a.w, off);
    }
    return a;
}

__device__ __forceinline__ void fma4(float4& a, float w, const float4& x) {
    a.x += w * x.x; a.y += w * x.y; a.z += w * x.z; a.w += w * x.w;
}

// ---------------------------------------------------------------------------
// Unified-range gather (R7, proven). One wave per node; lane = 16*q + m:
// quarter q handles edges s0+q+4k of the node's FULL contiguous edge range
// [s0,s4); m indexes a float4 of the 64-feature row. 4/2/1-deep pipelining.
// REL=1: masked per-relation accumulators; epilogue quad_reduce x4, quarter
//        q stores relation-q's row.          out: N x 256
// REL=0: 4 independent accumulator chains, summed; quarter 0 stores.
//                                             out: N x 64
// ---------------------------------------------------------------------------
template <int REL>
__global__ __launch_bounds__(256) void gather_k(
    const float* __restrict__ X, const int* __restrict__ rp2,
    const int2* __restrict__ pw, float* __restrict__ out, int N) {
    int node = blockIdx.x * 4 + (threadIdx.x >> 6);
    if (node >= N) return;
    int lane = threadIdx.x & 63;
    int q = lane >> 4, m = lane & 15;
    const int4 sv = *reinterpret_cast<const int4*>(rp2 + node * 4);
    const int s0 = sv.x, s1 = sv.y, s2 = sv.z, s3 = sv.w;
    const int s4 = rp2[node * 4 + 4];
    float4 A0 = make_float4(0.f, 0.f, 0.f, 0.f);
    float4 A1 = make_float4(0.f, 0.f, 0.f, 0.f);
    float4 A2 = make_float4(0.f, 0.f, 0.f, 0.f);
    float4 A3 = make_float4(0.f, 0.f, 0.f, 0.f);

    auto accum = [&](int idx, int slot, int2 e, const float4& xv) {
        float w = __int_as_float(e.y);
        if (REL) {
            fma4(A0, (idx < s1) ? w : 0.f, xv);
            fma4(A1, (idx >= s1 && idx < s2) ? w : 0.f, xv);
            fma4(A2, (idx >= s2 && idx < s3) ? w : 0.f, xv);
            fma4(A3, (idx >= s3) ? w : 0.f, xv);
        } else {
            if (slot == 0) fma4(A0, w, xv);
            else if (slot == 1) fma4(A1, w, xv);
            else if (slot == 2) fma4(A2, w, xv);
            else fma4(A3, w, xv);
        }
    };

    int i = s0 + q;
    for (; i + 12 < s4; i += 16) {  // 4 gathers in flight
        int2 e0 = pw[i];
        int2 e1 = pw[i + 4];
        int2 e2 = pw[i + 8];
        int2 e3 = pw[i + 12];
        float4 x0 = *reinterpret_cast<const float4*>(X + (size_t)e0.x * 64 + m * 4);
        float4 x1 = *reinterpret_cast<const float4*>(X + (size_t)e1.x * 64 + m * 4);
        float4 x2 = *reinterpret_cast<const float4*>(X + (size_t)e2.x * 64 + m * 4);
        float4 x3 = *reinterpret_cast<const float4*>(X + (size_t)e3.x * 64 + m * 4);
        accum(i, 0, e0, x0);
        accum(i + 4, 1, e1, x1);
        accum(i + 8, 2, e2, x2);
        accum(i + 12, 3, e3, x3);
    }
    for (; i + 4 < s4; i += 8) {  // 2 in flight
        int2 e0 = pw[i];
        int2 e1 = pw[i + 4];
        float4 x0 = *reinterpret_cast<const float4*>(X + (size_t)e0.x * 64 + m * 4);
        float4 x1 = *reinterpret_cast<const float4*>(X + (size_t)e1.x * 64 + m * 4);
        accum(i, 0, e0, x0);
        accum(i + 4, 1, e1, x1);
    }
    if (i < s4) {
        int2 e0 = pw[i];
        float4 x0 = *reinterpret_cast<const float4*>(X + (size_t)e0.x * 64 + m * 4);
        accum(i, 0, e0, x0);
    }

    if (REL) {
        A0 = quad_reduce(A0);
        A1 = quad_reduce(A1);
        A2 = quad_reduce(A2);
        A3 = quad_reduce(A3);
        float4 o = (q == 0) ? A0 : (q == 1) ? A1 : (q == 2) ? A2 : A3;
        *reinterpret_cast<float4*>(out + (size_t)node * 256 + q * 64 + m * 4) = o;
    } else {
        A0.x += A1.x + A2.x + A3.x;
        A0.y += A1.y + A2.y + A3.y;
        A0.z += A1.z + A2.z + A3.z;
        A0.w += A1.w + A2.w + A3.w;
        A0 = quad_reduce(A0);
        if (q == 0)
            *reinterpret_cast<float4*>(out + (size_t)node * 64 + m * 4) = A0;
    }
}

// ---------------------------------------------------------------------------
// Node-side tiled GEMM (deg from rp2 row bounds).
// MODE 0 (rgcn):  OUT = relu((X@B0 + AGG@B1) / deg)            OUT: N x 64
// MODE 1 (group): OUT = X + alpha*((AGG@B0)/deg + bias)        OUT: N x 64
// MODE 3 (group+head): g = X + alpha*((AGG@B0)/deg + bias);
//                      OUT = g@B1 + bias2                      OUT: N x 32
// ---------------------------------------------------------------------------
template <int MODE>
__global__ __launch_bounds__(256) void node_gemm(
    const float* __restrict__ X, const float* __restrict__ AGG,
    const float* __restrict__ B0, const float* __restrict__ B1,
    const float* __restrict__ bias, const float* __restrict__ bias2,
    const float* __restrict__ alphap, const int* __restrict__ rp2,
    float* __restrict__ OUT, int N) {
    __shared__ float As[64][68];
    __shared__ float Bs[64][64];
    const int tid = threadIdx.x;
    const int tx = tid & 15, ty = tid >> 4;
    const int row0 = blockIdx.x * 64;
    float acc[4][4] = {};

    const int nchunks = (MODE == 0) ? 5 : 1;
    for (int c = 0; c < nchunks; ++c) {
        const float* A;
        int lda;
        const float* B;
        if (MODE == 0) {
            if (c == 0) { A = X; lda = 64; B = B0; }
            else        { A = AGG + (c - 1) * 64; lda = 256; B = B1 + (size_t)(c - 1) * 64 * 64; }
        } else {
            A = AGG; lda = 64; B = B0;
        }
        if (c) __syncthreads();
#pragma unroll
        for (int q = 0; q < 4; ++q) {
            int f = q * 256 + tid;
            int r = f >> 4;
            int c4 = (f & 15) << 2;
            float4 v = make_float4(0.f, 0.f, 0.f, 0.f);
            int vr = row0 + r;
            if (vr < N) v = *reinterpret_cast<const float4*>(A + (size_t)vr * lda + c4);
            *reinterpret_cast<float4*>(&As[r][c4]) = v;
            *reinterpret_cast<float4*>(&Bs[r][c4]) =
                *reinterpret_cast<const float4*>(B + (size_t)r * 64 + c4);
        }
        __syncthreads();
#pragma unroll 8
        for (int k = 0; k < 64; ++k) {
            float4 b = *reinterpret_cast<const float4*>(&Bs[k][tx * 4]);
            float a0 = As[ty * 4 + 0][k];
            float a1 = As[ty * 4 + 1][k];
            float a2 = As[ty * 4 + 2][k];
            float a3 = As[ty * 4 + 3][k];
            acc[0][0] += a0 * b.x; acc[0][1] += a0 * b.y; acc[0][2] += a0 * b.z; acc[0][3] += a0 * b.w;
            acc[1][0] += a1 * b.x; acc[1][1] += a1 * b.y; acc[1][2] += a1 * b.z; acc[1][3] += a1 * b.w;
            acc[2][0] += a2 * b.x; acc[2][1] += a2 * b.y; acc[2][2] += a2 * b.z; acc[2][3] += a2 * b.w;
            acc[3][0] += a3 * b.x; acc[3][1] += a3 * b.y; acc[3][2] += a3 * b.z; acc[3][3] += a3 * b.w;
        }
    }

    const float alpha = (MODE == 1 || MODE == 3) ? alphap[0] : 0.f;

    if (MODE == 3) {
        // g = X + alpha*(acc/deg + bias) -> As (LDS); outW -> Bs; then
        // OUT = g @ outW + bias2 (64 -> 32).
        __syncthreads();  // main k-loop done everywhere before As/Bs reuse
#pragma unroll
        for (int i = 0; i < 4; ++i) {
            int vr = row0 + ty * 4 + i;
            float dg = 1.f;
            if (vr < N) dg = fmaxf((float)(rp2[vr * 4 + 4] - rp2[vr * 4]), 1.f);
#pragma unroll
            for (int j = 0; j < 4; ++j) {
                int col = tx * 4 + j;
                float g = 0.f;
                if (vr < N)
                    g = X[(size_t)vr * 64 + col] + alpha * (acc[i][j] / dg + bias[col]);
                As[ty * 4 + i][col] = g;
            }
        }
        // stage outW (64 x 32) into Bs[:][0..31]
#pragma unroll
        for (int t = 0; t < 2; ++t) {
            int idx = tid * 2 + t;        // 512 float4s
            int r = idx >> 3;
            int c4 = (idx & 7) << 2;
            *reinterpret_cast<float4*>(&Bs[r][c4]) =
                *reinterpret_cast<const float4*>(B1 + (size_t)r * 32 + c4);
        }
        __syncthreads();
        float acc2[4][2] = {};
#pragma unroll 8
        for (int k = 0; k < 64; ++k) {
            float b0 = Bs[k][tx * 2];
            float b1 = Bs[k][tx * 2 + 1];
#pragma unroll
            for (int i = 0; i < 4; ++i) {
                float a = As[ty * 4 + i][k];
                acc2[i][0] += a * b0;
                acc2[i][1] += a * b1;
            }
        }
#pragma unroll
        for (int i = 0; i < 4; ++i) {
            int vr = row0 + ty * 4 + i;
            if (vr >= N) continue;
#pragma unroll
            for (int j = 0; j < 2; ++j) {
                int col = tx * 2 + j;
                OUT[(size_t)vr * 32 + col] = acc2[i][j] + bias2[col];
            }
        }
        return;
    }

#pragma unroll
    for (int i = 0; i < 4; ++i) {
        int vr = row0 + ty * 4 + i;
        if (vr >= N) continue;
        float dg = fmaxf((float)(rp2[vr * 4 + 4] - rp2[vr * 4]), 1.f);
#pragma unroll
        for (int j = 0; j < 4; ++j) {
            int col = tx * 4 + j;
            if (MODE == 0) {
                OUT[(size_t)vr * 64 + col] = fmaxf(acc[i][j] / dg, 0.f);
            } else {
                OUT[(size_t)vr * 64 + col] =
                    X[(size_t)vr * 64 + col] + alpha * (acc[i][j] / dg + bias[col]);
            }
        }
    }
}

extern "C" void kernel_launch(void* const* d_in, const int* in_sizes, int n_in,
                              void* d_out, int out_size, void* d_ws, size_t ws_size,
                              hipStream_t stream) {
    const float* x      = (const float*)d_in[0];
    const int*   ei     = (const int*)d_in[1];
    const int*   et     = (const int*)d_in[2];
    const float* ew     = (const float*)d_in[3];
    const float* W1     = (const float*)d_in[4];
    const float* W01    = (const float*)d_in[5];
    const float* alpha1 = (const float*)d_in[6];
    const float* projW1 = (const float*)d_in[7];
    const float* projb1 = (const float*)d_in[8];
    const float* W2     = (const float*)d_in[9];
    const float* W02    = (const float*)d_in[10];
    const float* alpha2 = (const float*)d_in[11];
    const float* projW2 = (const float*)d_in[12];
    const float* projb2 = (const float*)d_in[13];
    const float* outW   = (const float*)d_in[14];
    const float* outb   = (const float*)d_in[15];
    const int N = in_sizes[0] / 64;
    const int E = in_sizes[2];
    const int M = 4 * N;            // (dst, rel) segments
    const int NB = (N + 255) >> 8;  // 256-node dst buckets

    // workspace (4-byte units):
    // bcnt[1024] | bofs[1032] | bcur[1024] | rp2[M+1 (+pad to even)] |
    // pw int2[E] | aggR[N*256] (recA int2[E] + recB int[E] aliased inside,
    // CSR-build only) | h[N*64] | g[N*64]
    int*   bcnt = (int*)d_ws;
    int*   bofs = bcnt + 1024;
    int*   bcur = bofs + 1032;
    int*   rp2  = bcur + 1024;
    int2*  pw   = (int2*)(rp2 + ((M + 2) & ~1));
    float* aggR = (float*)(pw + E);
    int2*  recA = (int2*)aggR;            // alias: dead once gather runs
    int*   recB = (int*)(recA + E);
    float* hbuf = aggR + (size_t)N * 256;
    float* gbuf = hbuf + (size_t)N * 64;

    const int gatherBlocks = (N + 3) / 4;
    const int gemmBlocks = (N + 63) / 64;
    const int pBlocks = (E + PART_EPB - 1) / PART_EPB;

    // ---- CSR build (block-aggregated radix partition, once per call) ----
    hipMemsetAsync(bcnt, 0, 1024 * sizeof(int), stream);
    bucket_hist<<<pBlocks, 256, 0, stream>>>(ei, bcnt, E, NB);
    bucket_scan<<<1, 1024, 0, stream>>>(bcnt, bofs, bcur, NB, E);
    partition<<<pBlocks, 256, 0, stream>>>(ei, et, ew, bcur, recA, recB, E, NB);
    bucket_fill<<<NB, 256, 0, stream>>>(recA, recB, bofs, rp2, pw, N);

    // ---- layer 1 ----
    gather_k<1><<<gatherBlocks, 256, 0, stream>>>(x, rp2, pw, aggR, N);
    node_gemm<0><<<gemmBlocks, 256, 0, stream>>>(x, aggR, W01, W1, nullptr, nullptr, nullptr, rp2, hbuf, N);
    gather_k<0><<<gatherBlocks, 256, 0, stream>>>(hbuf, rp2, pw, aggR, N);
    node_gemm<1><<<gemmBlocks, 256, 0, stream>>>(hbuf, aggR, projW1, nullptr, projb1, nullptr, alpha1, rp2, gbuf, N);

    // ---- layer 2 ----
    gather_k<1><<<gatherBlocks, 256, 0, stream>>>(gbuf, rp2, pw, aggR, N);
    node_gemm<0><<<gemmBlocks, 256, 0, stream>>>(gbuf, aggR, W02, W2, nullptr, nullptr, nullptr, rp2, hbuf, N);
    gather_k<0><<<gatherBlocks, 256, 0, stream>>>(hbuf, rp2, pw, aggR, N);
    // group + head fused: writes N x 32 output directly
    node_gemm<3><<<gemmBlocks, 256, 0, stream>>>(hbuf, aggR, projW2, outW, projb2, outb, alpha2, rp2, (float*)d_out, N);
}

// Round 10
// 427.090 us; speedup vs baseline: 1.1864x; 1.0212x over previous
//
#include <hip/hip_runtime.h>

// ---------------------------------------------------------------------------
// MR_GNN: 2x (RGCN + GroupEnhance) + linear head.
// R11 -> R12: structure frozen (R7 gathers at the ~4TB/s random-gather
// ceiling, tiled GEMMs, MODE3 head fusion, radix CSR build). Single change:
// the relation aggregate aggR (N x 256, written by gather_k<1>, read by
// node_gemm<0>) moves fp32 -> bf16 (RNE pack in the gather epilogue,
// unpack during GEMM LDS staging; all accumulation stays fp32). Cuts
// 2 x 51.2MB of pure intermediate traffic in half (~25us at 4TB/s).
// Group-path agg (N x 64) stays fp32.
// ---------------------------------------------------------------------------

#define PART_EPB 2048  // edges per partition/hist block (256 thr x 8)

// ---- CSR build, pass A1: per-bucket edge counts (bucket = dst >> 8) ----
__global__ __launch_bounds__(256) void bucket_hist(const int* __restrict__ ei,
                                                   int* __restrict__ bcnt,
                                                   int E, int NB) {
    __shared__ int h[1024];
    for (int i = threadIdx.x; i < 1024; i += 256) h[i] = 0;
    __syncthreads();
    int base = blockIdx.x * PART_EPB;
#pragma unroll
    for (int k = 0; k < PART_EPB / 256; ++k) {
        int e = base + k * 256 + threadIdx.x;
        if (e < E) atomicAdd(&h[ei[E + e] >> 8], 1);
    }
    __syncthreads();
    for (int i = threadIdx.x; i < NB; i += 256)
        if (h[i]) atomicAdd(&bcnt[i], h[i]);
}

// ---- pass A-scan: exclusive scan of NB (<=1024) bucket counts ----
__global__ __launch_bounds__(1024) void bucket_scan(const int* __restrict__ bcnt,
                                                    int* __restrict__ bofs,
                                                    int* __restrict__ bcur,
                                                    int NB, int E) {
    __shared__ int lds[1024];
    int tid = threadIdx.x;
    int v = (tid < NB) ? bcnt[tid] : 0;
    lds[tid] = v;
    __syncthreads();
    int acc = v;
    for (int off = 1; off < 1024; off <<= 1) {
        int t = (tid >= off) ? lds[tid - off] : 0;
        __syncthreads();
        acc += t;
        lds[tid] = acc;
        __syncthreads();
    }
    int excl = acc - v;
    if (tid < NB) { bofs[tid] = excl; bcur[tid] = excl; }
    if (tid == 0) bofs[NB] = E;
}

// ---- pass A2: block-aggregated partition into bucket streams ----
__global__ __launch_bounds__(256) void partition(const int* __restrict__ ei,
                                                 const int* __restrict__ et,
                                                 const float* __restrict__ ew,
                                                 int* __restrict__ gcur,
                                                 int2* __restrict__ recA,
                                                 int* __restrict__ recB,
                                                 int E, int NB) {
    __shared__ int hist[1024];
    __shared__ int base[1024];
    const int tid = threadIdx.x;
    const int blockBase = blockIdx.x * PART_EPB;
    for (int i = tid; i < 1024; i += 256) hist[i] = 0;
    __syncthreads();
#pragma unroll
    for (int k = 0; k < PART_EPB / 256; ++k) {
        int e = blockBase + k * 256 + tid;
        if (e < E) atomicAdd(&hist[ei[E + e] >> 8], 1);
    }
    __syncthreads();
    for (int i = tid; i < NB; i += 256) {
        int h = hist[i];
        base[i] = h ? atomicAdd(&gcur[i], h) : 0;
    }
    __syncthreads();
    for (int i = tid; i < 1024; i += 256) hist[i] = 0;  // reuse as run cursor
    __syncthreads();
#pragma unroll
    for (int k = 0; k < PART_EPB / 256; ++k) {
        int e = blockBase + k * 256 + tid;
        if (e >= E) continue;
        int dst = ei[E + e];
        int b = dst >> 8;
        int pos = base[b] + atomicAdd(&hist[b], 1);
        recA[pos] = make_int2(ei[e], __float_as_int(ew[e]));
        recB[pos] = dst * 4 + et[e];
    }
}

// ---- pass B: per-bucket (node,rel) hist + scan in LDS, write rp2 + pw ----
__global__ __launch_bounds__(256) void bucket_fill(
    const int2* __restrict__ recA, const int* __restrict__ recB,
    const int* __restrict__ bofs, int* __restrict__ rp2, int2* __restrict__ pw,
    int N) {
    __shared__ int cnt[1024];
    __shared__ int cur[1024];
    __shared__ int wsum[4];
    const int b = blockIdx.x;
    const int tid = threadIdx.x;
    const int beg = bofs[b], end = bofs[b + 1];
    const int rebase = b << 10;  // base index in (dst*4+rel) space
    for (int j = 0; j < 4; ++j) cnt[tid * 4 + j] = 0;
    __syncthreads();
    for (int i = beg + tid; i < end; i += 256)
        atomicAdd(&cnt[recB[i] - rebase], 1);
    __syncthreads();
    int v[4];
    int s = 0;
#pragma unroll
    for (int j = 0; j < 4; ++j) { v[j] = cnt[tid * 4 + j]; s += v[j]; }
    int lane = tid & 63, wid = tid >> 6;
    int ws = s;
#pragma unroll
    for (int off = 1; off < 64; off <<= 1) {
        int t = __shfl_up(ws, off);
        if (lane >= off) ws += t;
    }
    if (lane == 63) wsum[wid] = ws;
    __syncthreads();
    int wb = 0;
    for (int w = 0; w < wid; ++w) wb += wsum[w];
    int run = beg + wb + ws - s;
#pragma unroll
    for (int j = 0; j < 4; ++j) {
        int idx = rebase + tid * 4 + j;
        if (idx <= 4 * N) rp2[idx] = run;
        cur[tid * 4 + j] = run;
        run += v[j];
    }
    __syncthreads();
    for (int i = beg + tid; i < end; i += 256) {
        int l = recB[i] - rebase;
        int p = atomicAdd(&cur[l], 1);
        pw[p] = recA[i];
    }
}

__device__ __forceinline__ float4 quad_reduce(float4 a) {
#pragma unroll
    for (int off = 16; off < 64; off <<= 1) {
        a.x += __shfl_xor(a.x, off);
        a.y += __shfl_xor(a.y, off);
        a.z += __shfl_xor(a.z, off);
        a.w += __shfl_xor(a.w, off);
    }
    return a;
}

__device__ __forceinline__ void fma4(float4& a, float w, const float4& x) {
    a.x += w * x.x; a.y += w * x.y; a.z += w * x.z; a.w += w * x.w;
}

__device__ __forceinline__ unsigned short f2bf(float f) {
    unsigned u = __float_as_uint(f);
    unsigned r = u + 0x7fffu + ((u >> 16) & 1u);  // round-to-nearest-even
    return (unsigned short)(r >> 16);
}

__device__ __forceinline__ float bf2f(unsigned short h) {
    return __uint_as_float(((unsigned)h) << 16);
}

// ---------------------------------------------------------------------------
// Unified-range gather (R7, proven). One wave per node; lane = 16*q + m:
// quarter q handles edges s0+q+4k of the node's FULL contiguous edge range
// [s0,s4); m indexes a float4 of the 64-feature row. 4/2/1-deep pipelining.
// REL=1: masked per-relation accumulators; epilogue quad_reduce x4, quarter
//        q stores relation-q's row as bf16x4.  out: ushort N x 256
// REL=0: 4 independent accumulator chains, summed; quarter 0 stores fp32.
//                                               out: float N x 64
// ---------------------------------------------------------------------------
template <int REL>
__global__ __launch_bounds__(256) void gather_k(
    const float* __restrict__ X, const int* __restrict__ rp2,
    const int2* __restrict__ pw, void* __restrict__ outp, int N) {
    int node = blockIdx.x * 4 + (threadIdx.x >> 6);
    if (node >= N) return;
    int lane = threadIdx.x & 63;
    int q = lane >> 4, m = lane & 15;
    const int4 sv = *reinterpret_cast<const int4*>(rp2 + node * 4);
    const int s0 = sv.x, s1 = sv.y, s2 = sv.z, s3 = sv.w;
    const int s4 = rp2[node * 4 + 4];
    float4 A0 = make_float4(0.f, 0.f, 0.f, 0.f);
    float4 A1 = make_float4(0.f, 0.f, 0.f, 0.f);
    float4 A2 = make_float4(0.f, 0.f, 0.f, 0.f);
    float4 A3 = make_float4(0.f, 0.f, 0.f, 0.f);

    auto accum = [&](int idx, int slot, int2 e, const float4& xv) {
        float w = __int_as_float(e.y);
        if (REL) {
            fma4(A0, (idx < s1) ? w : 0.f, xv);
            fma4(A1, (idx >= s1 && idx < s2) ? w : 0.f, xv);
            fma4(A2, (idx >= s2 && idx < s3) ? w : 0.f, xv);
            fma4(A3, (idx >= s3) ? w : 0.f, xv);
        } else {
            if (slot == 0) fma4(A0, w, xv);
            else if (slot == 1) fma4(A1, w, xv);
            else if (slot == 2) fma4(A2, w, xv);
            else fma4(A3, w, xv);
        }
    };

    int i = s0 + q;
    for (; i + 12 < s4; i += 16) {  // 4 gathers in flight
        int2 e0 = pw[i];
        int2 e1 = pw[i + 4];
        int2 e2 = pw[i + 8];
        int2 e3 = pw[i + 12];
        float4 x0 = *reinterpret_cast<const float4*>(X + (size_t)e0.x * 64 + m * 4);
        float4 x1 = *reinterpret_cast<const float4*>(X + (size_t)e1.x * 64 + m * 4);
        float4 x2 = *reinterpret_cast<const float4*>(X + (size_t)e2.x * 64 + m * 4);
        float4 x3 = *reinterpret_cast<const float4*>(X + (size_t)e3.x * 64 + m * 4);
        accum(i, 0, e0, x0);
        accum(i + 4, 1, e1, x1);
        accum(i + 8, 2, e2, x2);
        accum(i + 12, 3, e3, x3);
    }
    for (; i + 4 < s4; i += 8) {  // 2 in flight
        int2 e0 = pw[i];
        int2 e1 = pw[i + 4];
        float4 x0 = *reinterpret_cast<const float4*>(X + (size_t)e0.x * 64 + m * 4);
        float4 x1 = *reinterpret_cast<const float4*>(X + (size_t)e1.x * 64 + m * 4);
        accum(i, 0, e0, x0);
        accum(i + 4, 1, e1, x1);
    }
    if (i < s4) {
        int2 e0 = pw[i];
        float4 x0 = *reinterpret_cast<const float4*>(X + (size_t)e0.x * 64 + m * 4);
        accum(i, 0, e0, x0);
    }

    if (REL) {
        A0 = quad_reduce(A0);
        A1 = quad_reduce(A1);
        A2 = quad_reduce(A2);
        A3 = quad_reduce(A3);
        float4 o = (q == 0) ? A0 : (q == 1) ? A1 : (q == 2) ? A2 : A3;
        ushort4 h = make_ushort4(f2bf(o.x), f2bf(o.y), f2bf(o.z), f2bf(o.w));
        *reinterpret_cast<ushort4*>((unsigned short*)outp +
                                    (size_t)node * 256 + q * 64 + m * 4) = h;
    } else {
        A0.x += A1.x + A2.x + A3.x;
        A0.y += A1.y + A2.y + A3.y;
        A0.z += A1.z + A2.z + A3.z;
        A0.w += A1.w + A2.w + A3.w;
        A0 = quad_reduce(A0);
        if (q == 0)
            *reinterpret_cast<float4*>((float*)outp + (size_t)node * 64 + m * 4) = A0;
    }
}

// ---------------------------------------------------------------------------
// Node-side tiled GEMM (deg from rp2 row bounds).
// MODE 0 (rgcn):  OUT = relu((X@B0 + AGGh@B1) / deg)           OUT: N x 64
//                 (AGGh is bf16 ushort N x 256)
// MODE 1 (group): OUT = X + alpha*((AGG@B0)/deg + bias)        OUT: N x 64
// MODE 3 (group+head): g = X + alpha*((AGG@B0)/deg + bias);
//                      OUT = g@B1 + bias2                      OUT: N x 32
// ---------------------------------------------------------------------------
template <int MODE>
__global__ __launch_bounds__(256) void node_gemm(
    const float* __restrict__ X, const float* __restrict__ AGG,
    const unsigned short* __restrict__ AGGh, const float* __restrict__ B0,
    const float* __restrict__ B1, const float* __restrict__ bias,
    const float* __restrict__ bias2, const float* __restrict__ alphap,
    const int* __restrict__ rp2, float* __restrict__ OUT, int N) {
    __shared__ float As[64][68];
    __shared__ float Bs[64][64];
    const int tid = threadIdx.x;
    const int tx = tid & 15, ty = tid >> 4;
    const int row0 = blockIdx.x * 64;
    float acc[4][4] = {};

    const int nchunks = (MODE == 0) ? 5 : 1;
    for (int c = 0; c < nchunks; ++c) {
        const float* B;
        if (MODE == 0) B = (c == 0) ? B0 : B1 + (size_t)(c - 1) * 64 * 64;
        else           B = B0;
        if (c) __syncthreads();
#pragma unroll
        for (int q = 0; q < 4; ++q) {
            int f = q * 256 + tid;
            int r = f >> 4;
            int c4 = (f & 15) << 2;
            int vr = row0 + r;
            float4 v = make_float4(0.f, 0.f, 0.f, 0.f);
            if (MODE == 0 && c > 0) {
                if (vr < N) {
                    ushort4 hv = *reinterpret_cast<const ushort4*>(
                        AGGh + (size_t)vr * 256 + (c - 1) * 64 + c4);
                    v = make_float4(bf2f(hv.x), bf2f(hv.y), bf2f(hv.z), bf2f(hv.w));
                }
            } else {
                const float* A = (MODE == 0) ? X : AGG;
                if (vr < N) v = *reinterpret_cast<const float4*>(A + (size_t)vr * 64 + c4);
            }
            *reinterpret_cast<float4*>(&As[r][c4]) = v;
            *reinterpret_cast<float4*>(&Bs[r][c4]) =
                *reinterpret_cast<const float4*>(B + (size_t)r * 64 + c4);
        }
        __syncthreads();
#pragma unroll 8
        for (int k = 0; k < 64; ++k) {
            float4 b = *reinterpret_cast<const float4*>(&Bs[k][tx * 4]);
            float a0 = As[ty * 4 + 0][k];
            float a1 = As[ty * 4 + 1][k];
            float a2 = As[ty * 4 + 2][k];
            float a3 = As[ty * 4 + 3][k];
            acc[0][0] += a0 * b.x; acc[0][1] += a0 * b.y; acc[0][2] += a0 * b.z; acc[0][3] += a0 * b.w;
            acc[1][0] += a1 * b.x; acc[1][1] += a1 * b.y; acc[1][2] += a1 * b.z; acc[1][3] += a1 * b.w;
            acc[2][0] += a2 * b.x; acc[2][1] += a2 * b.y; acc[2][2] += a2 * b.z; acc[2][3] += a2 * b.w;
            acc[3][0] += a3 * b.x; acc[3][1] += a3 * b.y; acc[3][2] += a3 * b.z; acc[3][3] += a3 * b.w;
        }
    }

    const float alpha = (MODE == 1 || MODE == 3) ? alphap[0] : 0.f;

    if (MODE == 3) {
        // g = X + alpha*(acc/deg + bias) -> As (LDS); outW -> Bs; then
        // OUT = g @ outW + bias2 (64 -> 32).
        __syncthreads();  // main k-loop done everywhere before As/Bs reuse
#pragma unroll
        for (int i = 0; i < 4; ++i) {
            int vr = row0 + ty * 4 + i;
            float dg = 1.f;
            if (vr < N) dg = fmaxf((float)(rp2[vr * 4 + 4] - rp2[vr * 4]), 1.f);
#pragma unroll
            for (int j = 0; j < 4; ++j) {
                int col = tx * 4 + j;
                float g = 0.f;
                if (vr < N)
                    g = X[(size_t)vr * 64 + col] + alpha * (acc[i][j] / dg + bias[col]);
                As[ty * 4 + i][col] = g;
            }
        }
        // stage outW (64 x 32) into Bs[:][0..31]
#pragma unroll
        for (int t = 0; t < 2; ++t) {
            int idx = tid * 2 + t;        // 512 float4s
            int r = idx >> 3;
            int c4 = (idx & 7) << 2;
            *reinterpret_cast<float4*>(&Bs[r][c4]) =
                *reinterpret_cast<const float4*>(B1 + (size_t)r * 32 + c4);
        }
        __syncthreads();
        float acc2[4][2] = {};
#pragma unroll 8
        for (int k = 0; k < 64; ++k) {
            float b0 = Bs[k][tx * 2];
            float b1 = Bs[k][tx * 2 + 1];
#pragma unroll
            for (int i = 0; i < 4; ++i) {
                float a = As[ty * 4 + i][k];
                acc2[i][0] += a * b0;
                acc2[i][1] += a * b1;
            }
        }
#pragma unroll
        for (int i = 0; i < 4; ++i) {
            int vr = row0 + ty * 4 + i;
            if (vr >= N) continue;
#pragma unroll
            for (int j = 0; j < 2; ++j) {
                int col = tx * 2 + j;
                OUT[(size_t)vr * 32 + col] = acc2[i][j] + bias2[col];
            }
        }
        return;
    }

#pragma unroll
    for (int i = 0; i < 4; ++i) {
        int vr = row0 + ty * 4 + i;
        if (vr >= N) continue;
        float dg = fmaxf((float)(rp2[vr * 4 + 4] - rp2[vr * 4]), 1.f);
#pragma unroll
        for (int j = 0; j < 4; ++j) {
            int col = tx * 4 + j;
            if (MODE == 0) {
                OUT[(size_t)vr * 64 + col] = fmaxf(acc[i][j] / dg, 0.f);
            } else {
                OUT[(size_t)vr * 64 + col] =
                    X[(size_t)vr * 64 + col] + alpha * (acc[i][j] / dg + bias[col]);
            }
        }
    }
}

extern "C" void kernel_launch(void* const* d_in, const int* in_sizes, int n_in,
                              void* d_out, int out_size, void* d_ws, size_t ws_size,
                              hipStream_t stream) {
    const float* x      = (const float*)d_in[0];
    const int*   ei     = (const int*)d_in[1];
    const int*   et     = (const int*)d_in[2];
    const float* ew     = (const float*)d_in[3];
    const float* W1     = (const float*)d_in[4];
    const float* W01    = (const float*)d_in[5];
    const float* alpha1 = (const float*)d_in[6];
    const float* projW1 = (const float*)d_in[7];
    const float* projb1 = (const float*)d_in[8];
    const float* W2     = (const float*)d_in[9];
    const float* W02    = (const float*)d_in[10];
    const float* alpha2 = (const float*)d_in[11];
    const float* projW2 = (const float*)d_in[12];
    const float* projb2 = (const float*)d_in[13];
    const float* outW   = (const float*)d_in[14];
    const float* outb   = (const float*)d_in[15];
    const int N = in_sizes[0] / 64;
    const int E = in_sizes[2];
    const int M = 4 * N;            // (dst, rel) segments
    const int NB = (N + 255) >> 8;  // 256-node dst buckets

    // workspace (4-byte units):
    // bcnt[1024] | bofs[1032] | bcur[1024] | rp2[M+1 (+pad to even)] |
    // pw int2[E] | aggR region (float-sized N*256; holds bf16 aggR N*256
    // ushorts AND fp32 group agg N*64; recA/recB aliased during CSR build) |
    // h[N*64] | g[N*64]
    int*   bcnt = (int*)d_ws;
    int*   bofs = bcnt + 1024;
    int*   bcur = bofs + 1032;
    int*   rp2  = bcur + 1024;
    int2*  pw   = (int2*)(rp2 + ((M + 2) & ~1));
    float* aggRegion = (float*)(pw + E);
    unsigned short* aggH = (unsigned short*)aggRegion;      // bf16 N x 256
    float* aggF = aggRegion + (size_t)N * 128;              // fp32 N x 64 (disjoint)
    int2*  recA = (int2*)aggRegion;       // alias: dead once gather runs
    int*   recB = (int*)(recA + E);
    float* hbuf = aggRegion + (size_t)N * 256;
    float* gbuf = hbuf + (size_t)N * 64;

    const int gatherBlocks = (N + 3) / 4;
    const int gemmBlocks = (N + 63) / 64;
    const int pBlocks = (E + PART_EPB - 1) / PART_EPB;

    // ---- CSR build (block-aggregated radix partition, once per call) ----
    hipMemsetAsync(bcnt, 0, 1024 * sizeof(int), stream);
    bucket_hist<<<pBlocks, 256, 0, stream>>>(ei, bcnt, E, NB);
    bucket_scan<<<1, 1024, 0, stream>>>(bcnt, bofs, bcur, NB, E);
    partition<<<pBlocks, 256, 0, stream>>>(ei, et, ew, bcur, recA, recB, E, NB);
    bucket_fill<<<NB, 256, 0, stream>>>(recA, recB, bofs, rp2, pw, N);

    // ---- layer 1 ----
    gather_k<1><<<gatherBlocks, 256, 0, stream>>>(x, rp2, pw, aggH, N);
    node_gemm<0><<<gemmBlocks, 256, 0, stream>>>(x, nullptr, aggH, W01, W1, nullptr, nullptr, nullptr, rp2, hbuf, N);
    gather_k<0><<<gatherBlocks, 256, 0, stream>>>(hbuf, rp2, pw, aggF, N);
    node_gemm<1><<<gemmBlocks, 256, 0, stream>>>(hbuf, aggF, nullptr, projW1, nullptr, projb1, nullptr, alpha1, rp2, gbuf, N);

    // ---- layer 2 ----
    gather_k<1><<<gatherBlocks, 256, 0, stream>>>(gbuf, rp2, pw, aggH, N);
    node_gemm<0><<<gemmBlocks, 256, 0, stream>>>(gbuf, nullptr, aggH, W02, W2, nullptr, nullptr, nullptr, rp2, hbuf, N);
    gather_k<0><<<gatherBlocks, 256, 0, stream>>>(hbuf, rp2, pw, aggF, N);
    // group + head fused: writes N x 32 output directly
    node_gemm<3><<<gemmBlocks, 256, 0, stream>>>(hbuf, aggF, nullptr, projW2, outW, projb2, outb, alpha2, rp2, (float*)d_out, N);
}

// Round 11
// 400.248 us; speedup vs baseline: 1.2660x; 1.0671x over previous
//
#include <hip/hip_runtime.h>

// ---------------------------------------------------------------------------
// MR_GNN: 2x (RGCN + GroupEnhance) + linear head.
// R12 -> R13: gathers' FETCH (137MB each) is random 256B fp32 row reads of a
// 12.8MB table thrashing the 4MB/XCD L2. Extend the validated bf16 trick to
// the gather INPUT: maintain a bf16 shadow of the feature table (xb for x,
// hb/gb written in the GEMM epilogues). Rows drop to 128B, table to 6.4MB ->
// fewer miss bytes AND higher hit rate. All accumulation, residuals, and
// GEMM operands stay fp32. Shadow buffers live in aggRegion's unused upper
// quarter (xb/gb alias: xb dead after L1 gather; all disjoint from aggH,
// aggF, and the CSR-build recA/recB alias).
// ---------------------------------------------------------------------------

#define PART_EPB 2048  // edges per partition/hist block (256 thr x 8)

// ---- CSR build, pass A1: per-bucket edge counts (bucket = dst >> 8) ----
__global__ __launch_bounds__(256) void bucket_hist(const int* __restrict__ ei,
                                                   int* __restrict__ bcnt,
                                                   int E, int NB) {
    __shared__ int h[1024];
    for (int i = threadIdx.x; i < 1024; i += 256) h[i] = 0;
    __syncthreads();
    int base = blockIdx.x * PART_EPB;
#pragma unroll
    for (int k = 0; k < PART_EPB / 256; ++k) {
        int e = base + k * 256 + threadIdx.x;
        if (e < E) atomicAdd(&h[ei[E + e] >> 8], 1);
    }
    __syncthreads();
    for (int i = threadIdx.x; i < NB; i += 256)
        if (h[i]) atomicAdd(&bcnt[i], h[i]);
}

// ---- pass A-scan: exclusive scan of NB (<=1024) bucket counts ----
__global__ __launch_bounds__(1024) void bucket_scan(const int* __restrict__ bcnt,
                                                    int* __restrict__ bofs,
                                                    int* __restrict__ bcur,
                                                    int NB, int E) {
    __shared__ int lds[1024];
    int tid = threadIdx.x;
    int v = (tid < NB) ? bcnt[tid] : 0;
    lds[tid] = v;
    __syncthreads();
    int acc = v;
    for (int off = 1; off < 1024; off <<= 1) {
        int t = (tid >= off) ? lds[tid - off] : 0;
        __syncthreads();
        acc += t;
        lds[tid] = acc;
        __syncthreads();
    }
    int excl = acc - v;
    if (tid < NB) { bofs[tid] = excl; bcur[tid] = excl; }
    if (tid == 0) bofs[NB] = E;
}

// ---- pass A2: block-aggregated partition into bucket streams ----
__global__ __launch_bounds__(256) void partition(const int* __restrict__ ei,
                                                 const int* __restrict__ et,
                                                 const float* __restrict__ ew,
                                                 int* __restrict__ gcur,
                                                 int2* __restrict__ recA,
                                                 int* __restrict__ recB,
                                                 int E, int NB) {
    __shared__ int hist[1024];
    __shared__ int base[1024];
    const int tid = threadIdx.x;
    const int blockBase = blockIdx.x * PART_EPB;
    for (int i = tid; i < 1024; i += 256) hist[i] = 0;
    __syncthreads();
#pragma unroll
    for (int k = 0; k < PART_EPB / 256; ++k) {
        int e = blockBase + k * 256 + tid;
        if (e < E) atomicAdd(&hist[ei[E + e] >> 8], 1);
    }
    __syncthreads();
    for (int i = tid; i < NB; i += 256) {
        int h = hist[i];
        base[i] = h ? atomicAdd(&gcur[i], h) : 0;
    }
    __syncthreads();
    for (int i = tid; i < 1024; i += 256) hist[i] = 0;  // reuse as run cursor
    __syncthreads();
#pragma unroll
    for (int k = 0; k < PART_EPB / 256; ++k) {
        int e = blockBase + k * 256 + tid;
        if (e >= E) continue;
        int dst = ei[E + e];
        int b = dst >> 8;
        int pos = base[b] + atomicAdd(&hist[b], 1);
        recA[pos] = make_int2(ei[e], __float_as_int(ew[e]));
        recB[pos] = dst * 4 + et[e];
    }
}

// ---- pass B: per-bucket (node,rel) hist + scan in LDS, write rp2 + pw ----
__global__ __launch_bounds__(256) void bucket_fill(
    const int2* __restrict__ recA, const int* __restrict__ recB,
    const int* __restrict__ bofs, int* __restrict__ rp2, int2* __restrict__ pw,
    int N) {
    __shared__ int cnt[1024];
    __shared__ int cur[1024];
    __shared__ int wsum[4];
    const int b = blockIdx.x;
    const int tid = threadIdx.x;
    const int beg = bofs[b], end = bofs[b + 1];
    const int rebase = b << 10;  // base index in (dst*4+rel) space
    for (int j = 0; j < 4; ++j) cnt[tid * 4 + j] = 0;
    __syncthreads();
    for (int i = beg + tid; i < end; i += 256)
        atomicAdd(&cnt[recB[i] - rebase], 1);
    __syncthreads();
    int v[4];
    int s = 0;
#pragma unroll
    for (int j = 0; j < 4; ++j) { v[j] = cnt[tid * 4 + j]; s += v[j]; }
    int lane = tid & 63, wid = tid >> 6;
    int ws = s;
#pragma unroll
    for (int off = 1; off < 64; off <<= 1) {
        int t = __shfl_up(ws, off);
        if (lane >= off) ws += t;
    }
    if (lane == 63) wsum[wid] = ws;
    __syncthreads();
    int wb = 0;
    for (int w = 0; w < wid; ++w) wb += wsum[w];
    int run = beg + wb + ws - s;
#pragma unroll
    for (int j = 0; j < 4; ++j) {
        int idx = rebase + tid * 4 + j;
        if (idx <= 4 * N) rp2[idx] = run;
        cur[tid * 4 + j] = run;
        run += v[j];
    }
    __syncthreads();
    for (int i = beg + tid; i < end; i += 256) {
        int l = recB[i] - rebase;
        int p = atomicAdd(&cur[l], 1);
        pw[p] = recA[i];
    }
}

__device__ __forceinline__ float4 quad_reduce(float4 a) {
#pragma unroll
    for (int off = 16; off < 64; off <<= 1) {
        a.x += __shfl_xor(a.x, off);
        a.y += __shfl_xor(a.y, off);
        a.z += __shfl_xor(a.z, off);
        a.w += __shfl_xor(a.w, off);
    }
    return a;
}

__device__ __forceinline__ void fma4(float4& a, float w, const float4& x) {
    a.x += w * x.x; a.y += w * x.y; a.z += w * x.z; a.w += w * x.w;
}

__device__ __forceinline__ unsigned short f2bf(float f) {
    unsigned u = __float_as_uint(f);
    unsigned r = u + 0x7fffu + ((u >> 16) & 1u);  // round-to-nearest-even
    return (unsigned short)(r >> 16);
}

__device__ __forceinline__ float bf2f(unsigned short h) {
    return __uint_as_float(((unsigned)h) << 16);
}

__device__ __forceinline__ float4 bf2f4(ushort4 h) {
    return make_float4(bf2f(h.x), bf2f(h.y), bf2f(h.z), bf2f(h.w));
}

// ---- fp32 -> bf16 table cast (for x; sequential, ~2us) ----
__global__ __launch_bounds__(256) void cast_bf16(const float* __restrict__ in,
                                                 unsigned short* __restrict__ out,
                                                 int n4) {
    int i = blockIdx.x * 256 + threadIdx.x;
    if (i >= n4) return;
    float4 v = reinterpret_cast<const float4*>(in)[i];
    reinterpret_cast<ushort4*>(out)[i] =
        make_ushort4(f2bf(v.x), f2bf(v.y), f2bf(v.z), f2bf(v.w));
}

// ---------------------------------------------------------------------------
// Unified-range gather (R7 structure, proven; input now bf16 shadow table).
// One wave per node; lane = 16*q + m: quarter q handles edges s0+q+4k of the
// node's FULL contiguous edge range [s0,s4); m indexes a ushort4 (4 feats)
// of the 64-feature bf16 row (128B/row). 4/2/1-deep pipelining.
// REL=1: masked per-relation accumulators; quad_reduce x4; quarter q stores
//        relation-q's row as bf16x4.          out: ushort N x 256
// REL=0: 4 independent accumulator chains, summed; quarter 0 stores fp32.
//                                              out: float N x 64
// ---------------------------------------------------------------------------
template <int REL>
__global__ __launch_bounds__(256) void gather_k(
    const unsigned short* __restrict__ Xb, const int* __restrict__ rp2,
    const int2* __restrict__ pw, void* __restrict__ outp, int N) {
    int node = blockIdx.x * 4 + (threadIdx.x >> 6);
    if (node >= N) return;
    int lane = threadIdx.x & 63;
    int q = lane >> 4, m = lane & 15;
    const int4 sv = *reinterpret_cast<const int4*>(rp2 + node * 4);
    const int s0 = sv.x, s1 = sv.y, s2 = sv.z, s3 = sv.w;
    const int s4 = rp2[node * 4 + 4];
    float4 A0 = make_float4(0.f, 0.f, 0.f, 0.f);
    float4 A1 = make_float4(0.f, 0.f, 0.f, 0.f);
    float4 A2 = make_float4(0.f, 0.f, 0.f, 0.f);
    float4 A3 = make_float4(0.f, 0.f, 0.f, 0.f);

    auto accum = [&](int idx, int slot, int2 e, const float4& xv) {
        float w = __int_as_float(e.y);
        if (REL) {
            fma4(A0, (idx < s1) ? w : 0.f, xv);
            fma4(A1, (idx >= s1 && idx < s2) ? w : 0.f, xv);
            fma4(A2, (idx >= s2 && idx < s3) ? w : 0.f, xv);
            fma4(A3, (idx >= s3) ? w : 0.f, xv);
        } else {
            if (slot == 0) fma4(A0, w, xv);
            else if (slot == 1) fma4(A1, w, xv);
            else if (slot == 2) fma4(A2, w, xv);
            else fma4(A3, w, xv);
        }
    };

    int i = s0 + q;
    for (; i + 12 < s4; i += 16) {  // 4 gathers in flight
        int2 e0 = pw[i];
        int2 e1 = pw[i + 4];
        int2 e2 = pw[i + 8];
        int2 e3 = pw[i + 12];
        ushort4 h0 = *reinterpret_cast<const ushort4*>(Xb + (size_t)e0.x * 64 + m * 4);
        ushort4 h1 = *reinterpret_cast<const ushort4*>(Xb + (size_t)e1.x * 64 + m * 4);
        ushort4 h2 = *reinterpret_cast<const ushort4*>(Xb + (size_t)e2.x * 64 + m * 4);
        ushort4 h3 = *reinterpret_cast<const ushort4*>(Xb + (size_t)e3.x * 64 + m * 4);
        accum(i, 0, e0, bf2f4(h0));
        accum(i + 4, 1, e1, bf2f4(h1));
        accum(i + 8, 2, e2, bf2f4(h2));
        accum(i + 12, 3, e3, bf2f4(h3));
    }
    for (; i + 4 < s4; i += 8) {  // 2 in flight
        int2 e0 = pw[i];
        int2 e1 = pw[i + 4];
        ushort4 h0 = *reinterpret_cast<const ushort4*>(Xb + (size_t)e0.x * 64 + m * 4);
        ushort4 h1 = *reinterpret_cast<const ushort4*>(Xb + (size_t)e1.x * 64 + m * 4);
        accum(i, 0, e0, bf2f4(h0));
        accum(i + 4, 1, e1, bf2f4(h1));
    }
    if (i < s4) {
        int2 e0 = pw[i];
        ushort4 h0 = *reinterpret_cast<const ushort4*>(Xb + (size_t)e0.x * 64 + m * 4);
        accum(i, 0, e0, bf2f4(h0));
    }

    if (REL) {
        A0 = quad_reduce(A0);
        A1 = quad_reduce(A1);
        A2 = quad_reduce(A2);
        A3 = quad_reduce(A3);
        float4 o = (q == 0) ? A0 : (q == 1) ? A1 : (q == 2) ? A2 : A3;
        ushort4 h = make_ushort4(f2bf(o.x), f2bf(o.y), f2bf(o.z), f2bf(o.w));
        *reinterpret_cast<ushort4*>((unsigned short*)outp +
                                    (size_t)node * 256 + q * 64 + m * 4) = h;
    } else {
        A0.x += A1.x + A2.x + A3.x;
        A0.y += A1.y + A2.y + A3.y;
        A0.z += A1.z + A2.z + A3.z;
        A0.w += A1.w + A2.w + A3.w;
        A0 = quad_reduce(A0);
        if (q == 0)
            *reinterpret_cast<float4*>((float*)outp + (size_t)node * 64 + m * 4) = A0;
    }
}

// ---------------------------------------------------------------------------
// Node-side tiled GEMM (deg from rp2 row bounds).
// MODE 0 (rgcn):  OUT = relu((X@B0 + AGGh@B1) / deg)           OUT: N x 64
//                 (AGGh bf16; also writes OUTb = bf16 copy of OUT)
// MODE 1 (group): OUT = X + alpha*((AGG@B0)/deg + bias)        OUT: N x 64
//                 (also writes OUTb)
// MODE 3 (group+head): g = X + alpha*((AGG@B0)/deg + bias);
//                      OUT = g@B1 + bias2                      OUT: N x 32
// ---------------------------------------------------------------------------
template <int MODE>
__global__ __launch_bounds__(256) void node_gemm(
    const float* __restrict__ X, const float* __restrict__ AGG,
    const unsigned short* __restrict__ AGGh, const float* __restrict__ B0,
    const float* __restrict__ B1, const float* __restrict__ bias,
    const float* __restrict__ bias2, const float* __restrict__ alphap,
    const int* __restrict__ rp2, float* __restrict__ OUT,
    unsigned short* __restrict__ OUTb, int N) {
    __shared__ float As[64][68];
    __shared__ float Bs[64][64];
    const int tid = threadIdx.x;
    const int tx = tid & 15, ty = tid >> 4;
    const int row0 = blockIdx.x * 64;
    float acc[4][4] = {};

    const int nchunks = (MODE == 0) ? 5 : 1;
    for (int c = 0; c < nchunks; ++c) {
        const float* B;
        if (MODE == 0) B = (c == 0) ? B0 : B1 + (size_t)(c - 1) * 64 * 64;
        else           B = B0;
        if (c) __syncthreads();
#pragma unroll
        for (int q = 0; q < 4; ++q) {
            int f = q * 256 + tid;
            int r = f >> 4;
            int c4 = (f & 15) << 2;
            int vr = row0 + r;
            float4 v = make_float4(0.f, 0.f, 0.f, 0.f);
            if (MODE == 0 && c > 0) {
                if (vr < N) {
                    ushort4 hv = *reinterpret_cast<const ushort4*>(
                        AGGh + (size_t)vr * 256 + (c - 1) * 64 + c4);
                    v = bf2f4(hv);
                }
            } else {
                const float* A = (MODE == 0) ? X : AGG;
                if (vr < N) v = *reinterpret_cast<const float4*>(A + (size_t)vr * 64 + c4);
            }
            *reinterpret_cast<float4*>(&As[r][c4]) = v;
            *reinterpret_cast<float4*>(&Bs[r][c4]) =
                *reinterpret_cast<const float4*>(B + (size_t)r * 64 + c4);
        }
        __syncthreads();
#pragma unroll 8
        for (int k = 0; k < 64; ++k) {
            float4 b = *reinterpret_cast<const float4*>(&Bs[k][tx * 4]);
            float a0 = As[ty * 4 + 0][k];
            float a1 = As[ty * 4 + 1][k];
            float a2 = As[ty * 4 + 2][k];
            float a3 = As[ty * 4 + 3][k];
            acc[0][0] += a0 * b.x; acc[0][1] += a0 * b.y; acc[0][2] += a0 * b.z; acc[0][3] += a0 * b.w;
            acc[1][0] += a1 * b.x; acc[1][1] += a1 * b.y; acc[1][2] += a1 * b.z; acc[1][3] += a1 * b.w;
            acc[2][0] += a2 * b.x; acc[2][1] += a2 * b.y; acc[2][2] += a2 * b.z; acc[2][3] += a2 * b.w;
            acc[3][0] += a3 * b.x; acc[3][1] += a3 * b.y; acc[3][2] += a3 * b.z; acc[3][3] += a3 * b.w;
        }
    }

    const float alpha = (MODE == 1 || MODE == 3) ? alphap[0] : 0.f;

    if (MODE == 3) {
        // g = X + alpha*(acc/deg + bias) -> As (LDS); outW -> Bs; then
        // OUT = g @ outW + bias2 (64 -> 32).
        __syncthreads();  // main k-loop done everywhere before As/Bs reuse
#pragma unroll
        for (int i = 0; i < 4; ++i) {
            int vr = row0 + ty * 4 + i;
            float dg = 1.f;
            if (vr < N) dg = fmaxf((float)(rp2[vr * 4 + 4] - rp2[vr * 4]), 1.f);
#pragma unroll
            for (int j = 0; j < 4; ++j) {
                int col = tx * 4 + j;
                float g = 0.f;
                if (vr < N)
                    g = X[(size_t)vr * 64 + col] + alpha * (acc[i][j] / dg + bias[col]);
                As[ty * 4 + i][col] = g;
            }
        }
        // stage outW (64 x 32) into Bs[:][0..31]
#pragma unroll
        for (int t = 0; t < 2; ++t) {
            int idx = tid * 2 + t;        // 512 float4s
            int r = idx >> 3;
            int c4 = (idx & 7) << 2;
            *reinterpret_cast<float4*>(&Bs[r][c4]) =
                *reinterpret_cast<const float4*>(B1 + (size_t)r * 32 + c4);
        }
        __syncthreads();
        float acc2[4][2] = {};
#pragma unroll 8
        for (int k = 0; k < 64; ++k) {
            float b0 = Bs[k][tx * 2];
            float b1 = Bs[k][tx * 2 + 1];
#pragma unroll
            for (int i = 0; i < 4; ++i) {
                float a = As[ty * 4 + i][k];
                acc2[i][0] += a * b0;
                acc2[i][1] += a * b1;
            }
        }
#pragma unroll
        for (int i = 0; i < 4; ++i) {
            int vr = row0 + ty * 4 + i;
            if (vr >= N) continue;
#pragma unroll
            for (int j = 0; j < 2; ++j) {
                int col = tx * 2 + j;
                OUT[(size_t)vr * 32 + col] = acc2[i][j] + bias2[col];
            }
        }
        return;
    }

#pragma unroll
    for (int i = 0; i < 4; ++i) {
        int vr = row0 + ty * 4 + i;
        if (vr >= N) continue;
        float dg = fmaxf((float)(rp2[vr * 4 + 4] - rp2[vr * 4]), 1.f);
        float4 o;
#pragma unroll
        for (int j = 0; j < 4; ++j) {
            int col = tx * 4 + j;
            float v;
            if (MODE == 0) {
                v = fmaxf(acc[i][j] / dg, 0.f);
            } else {
                v = X[(size_t)vr * 64 + col] + alpha * (acc[i][j] / dg + bias[col]);
            }
            OUT[(size_t)vr * 64 + col] = v;
            (&o.x)[j] = v;
        }
        // bf16 shadow row for the next gather's random reads
        *reinterpret_cast<ushort4*>(OUTb + (size_t)vr * 64 + tx * 4) =
            make_ushort4(f2bf(o.x), f2bf(o.y), f2bf(o.z), f2bf(o.w));
    }
}

extern "C" void kernel_launch(void* const* d_in, const int* in_sizes, int n_in,
                              void* d_out, int out_size, void* d_ws, size_t ws_size,
                              hipStream_t stream) {
    const float* x      = (const float*)d_in[0];
    const int*   ei     = (const int*)d_in[1];
    const int*   et     = (const int*)d_in[2];
    const float* ew     = (const float*)d_in[3];
    const float* W1     = (const float*)d_in[4];
    const float* W01    = (const float*)d_in[5];
    const float* alpha1 = (const float*)d_in[6];
    const float* projW1 = (const float*)d_in[7];
    const float* projb1 = (const float*)d_in[8];
    const float* W2     = (const float*)d_in[9];
    const float* W02    = (const float*)d_in[10];
    const float* alpha2 = (const float*)d_in[11];
    const float* projW2 = (const float*)d_in[12];
    const float* projb2 = (const float*)d_in[13];
    const float* outW   = (const float*)d_in[14];
    const float* outb   = (const float*)d_in[15];
    const int N = in_sizes[0] / 64;
    const int E = in_sizes[2];
    const int M = 4 * N;            // (dst, rel) segments
    const int NB = (N + 255) >> 8;  // 256-node dst buckets

    // workspace (4-byte units):
    // bcnt[1024] | bofs[1032] | bcur[1024] | rp2[M+1 (+pad to even)] |
    // pw int2[E] | aggRegion (N*256 floats):
    //     [0,      N*128)  aggH   bf16 N x 256  (relation agg)
    //     [N*128,  N*192)  aggF   fp32 N x 64   (group agg)
    //     [N*192,  N*224)  xb/gb  bf16 N x 64   (shadow: x, then g)
    //     [N*224,  N*256)  hb     bf16 N x 64   (shadow: h)
    //     (recA int2[E] + recB int[E] alias the front during CSR build only)
    // | h[N*64] | g[N*64]
    int*   bcnt = (int*)d_ws;
    int*   bofs = bcnt + 1024;
    int*   bcur = bofs + 1032;
    int*   rp2  = bcur + 1024;
    int2*  pw   = (int2*)(rp2 + ((M + 2) & ~1));
    float* aggRegion = (float*)(pw + E);
    unsigned short* aggH = (unsigned short*)aggRegion;              // bf16 N x 256
    float* aggF = aggRegion + (size_t)N * 128;                      // fp32 N x 64
    unsigned short* xb = (unsigned short*)(aggRegion + (size_t)N * 192);  // also gb
    unsigned short* hb = (unsigned short*)(aggRegion + (size_t)N * 224);
    int2*  recA = (int2*)aggRegion;       // alias: dead once gathers run
    int*   recB = (int*)(recA + E);
    float* hbuf = aggRegion + (size_t)N * 256;
    float* gbuf = hbuf + (size_t)N * 64;

    const int gatherBlocks = (N + 3) / 4;
    const int gemmBlocks = (N + 63) / 64;
    const int pBlocks = (E + PART_EPB - 1) / PART_EPB;

    // ---- CSR build (block-aggregated radix partition, once per call) ----
    hipMemsetAsync(bcnt, 0, 1024 * sizeof(int), stream);
    bucket_hist<<<pBlocks, 256, 0, stream>>>(ei, bcnt, E, NB);
    bucket_scan<<<1, 1024, 0, stream>>>(bcnt, bofs, bcur, NB, E);
    partition<<<pBlocks, 256, 0, stream>>>(ei, et, ew, bcur, recA, recB, E, NB);
    bucket_fill<<<NB, 256, 0, stream>>>(recA, recB, bofs, rp2, pw, N);
    cast_bf16<<<(N * 16 + 255) / 256, 256, 0, stream>>>(x, xb, N * 16);

    // ---- layer 1 ----
    gather_k<1><<<gatherBlocks, 256, 0, stream>>>(xb, rp2, pw, aggH, N);
    node_gemm<0><<<gemmBlocks, 256, 0, stream>>>(x, nullptr, aggH, W01, W1, nullptr, nullptr, nullptr, rp2, hbuf, hb, N);
    gather_k<0><<<gatherBlocks, 256, 0, stream>>>(hb, rp2, pw, aggF, N);
    node_gemm<1><<<gemmBlocks, 256, 0, stream>>>(hbuf, aggF, nullptr, projW1, nullptr, projb1, nullptr, alpha1, rp2, gbuf, xb /*gb*/, N);

    // ---- layer 2 ----
    gather_k<1><<<gatherBlocks, 256, 0, stream>>>(xb /*gb*/, rp2, pw, aggH, N);
    node_gemm<0><<<gemmBlocks, 256, 0, stream>>>(gbuf, nullptr, aggH, W02, W2, nullptr, nullptr, nullptr, rp2, hbuf, hb, N);
    gather_k<0><<<gatherBlocks, 256, 0, stream>>>(hb, rp2, pw, aggF, N);
    // group + head fused: writes N x 32 output directly
    node_gemm<3><<<gemmBlocks, 256, 0, stream>>>(hbuf, aggF, nullptr, projW2, outW, projb2, outb, alpha2, rp2, (float*)d_out, nullptr, N);
}